// Round 4
// baseline (748.334 us; speedup 1.0000x reference)
//
#include <hip/hip_runtime.h>
#include <hip/hip_bf16.h>
#include <math.h>

// ---------------------------------------------------------------------------
// 2-layer GAT (H=1, D=128) on MI355X.
// Per layer:  hs = x @ W_src            (SIMT f32 GEMM, 128-wide)
//             al_s[n] = x[n]·(W_src@a_src),  al_d[n] = x[n]·(W_dst@a_dst)
//             per-dst-node softmax over in-edges + weighted sum of hs[src]
// CSR (by dst) built once on device, reused by both layers.
// ---------------------------------------------------------------------------

#define WAVE 64

// ---- tiny: wv[k] = sum_d W[k*128+d] * a[d] --------------------------------
__global__ void make_wv_kernel(const float* __restrict__ W,
                               const float* __restrict__ a,
                               float* __restrict__ wv) {
    int k = threadIdx.x;  // 128 threads
    float s = 0.f;
    for (int d = 0; d < 128; ++d) s += W[k * 128 + d] * a[d];
    wv[k] = s;
}

// ---- al_s / al_d ----------------------------------------------------------
__global__ void compute_al_kernel(const float* __restrict__ X,
                                  const float* __restrict__ wsv,
                                  const float* __restrict__ wdv,
                                  float* __restrict__ al_s,
                                  float* __restrict__ al_d, int N) {
    int node = (int)((blockIdx.x * (unsigned)blockDim.x + threadIdx.x) >> 6);
    int lane = threadIdx.x & 63;
    if (node >= N) return;
    float2 xv = *(const float2*)&X[(size_t)node * 128 + lane * 2];
    float2 sv = *(const float2*)&wsv[lane * 2];
    float2 dv = *(const float2*)&wdv[lane * 2];
    float ps = xv.x * sv.x + xv.y * sv.y;
    float pd = xv.x * dv.x + xv.y * dv.y;
    for (int o = 32; o >= 1; o >>= 1) {
        ps += __shfl_xor(ps, o);
        pd += __shfl_xor(pd, o);
    }
    if (lane == 0) { al_s[node] = ps; al_d[node] = pd; }
}

// ---- CSR build ------------------------------------------------------------
__global__ void hist_kernel(const int* __restrict__ dst, int* __restrict__ cnt,
                            int E) {
    int i = blockIdx.x * blockDim.x + threadIdx.x;
    if (i < E) atomicAdd(&cnt[dst[i]], 1);
}

__global__ void scan1_kernel(const int* __restrict__ cnt, int* __restrict__ out,
                             int* __restrict__ aux, int N) {
    __shared__ int sh[1024];
    int i = blockIdx.x * 1024 + threadIdx.x;
    int v = (i < N) ? cnt[i] : 0;
    sh[threadIdx.x] = v;
    __syncthreads();
    for (int o = 1; o < 1024; o <<= 1) {
        int t = (threadIdx.x >= o) ? sh[threadIdx.x - o] : 0;
        __syncthreads();
        sh[threadIdx.x] += t;
        __syncthreads();
    }
    if (i < N) out[i] = sh[threadIdx.x] - v;  // exclusive
    if (threadIdx.x == 1023) aux[blockIdx.x] = sh[1023];
}

__global__ void scan2_kernel(int* __restrict__ aux, int nb) {
    if (blockIdx.x == 0 && threadIdx.x == 0) {
        int run = 0;
        for (int i = 0; i < nb; ++i) { int v = aux[i]; aux[i] = run; run += v; }
    }
}

__global__ void scan3_kernel(int* __restrict__ row_ptr, int* __restrict__ nxt,
                             const int* __restrict__ aux, int N, int E) {
    int i = blockIdx.x * 1024 + threadIdx.x;
    if (i < N) {
        int v = row_ptr[i] + aux[blockIdx.x];
        row_ptr[i] = v;
        nxt[i] = v;
    }
    if (i == 0) row_ptr[N] = E;
}

__global__ void scatter_kernel(const int* __restrict__ src,
                               const int* __restrict__ dst,
                               int* __restrict__ nxt, int* __restrict__ col,
                               int E) {
    int i = blockIdx.x * blockDim.x + threadIdx.x;
    if (i < E) {
        int p = atomicAdd(&nxt[dst[i]], 1);
        col[p] = src[i];
    }
}

// ---- GEMM: C[N,128] = X[N,128] @ W[128,128], f32 SIMT ---------------------
__global__ __launch_bounds__(256) void gemm128_kernel(
    const float* __restrict__ X, const float* __restrict__ W,
    float* __restrict__ C, int N) {
    __shared__ float Xs[16][132];
    __shared__ float Ws[16][132];
    const int tid = threadIdx.x;
    const int row0 = blockIdx.x * 128;
    const int rg = tid >> 4, cg = tid & 15;
    const int tr = rg * 8, tc = cg * 8;
    float acc[8][8];
#pragma unroll
    for (int i = 0; i < 8; ++i)
#pragma unroll
        for (int j = 0; j < 8; ++j) acc[i][j] = 0.f;

    const int r1 = tid >> 2;            // 0..63
    const int kq = (tid & 3) * 4;       // 0,4,8,12
    const int kk = tid >> 5;            // 0..7
    const int c4 = (tid & 31) * 4;      // 0..124

    for (int kb = 0; kb < 128; kb += 16) {
        // stage X (transposed) ------------------------------------------------
        {
            int gr = row0 + r1;
            float4 v = make_float4(0.f, 0.f, 0.f, 0.f);
            if (gr < N) v = *(const float4*)&X[(size_t)gr * 128 + kb + kq];
            Xs[kq + 0][r1] = v.x; Xs[kq + 1][r1] = v.y;
            Xs[kq + 2][r1] = v.z; Xs[kq + 3][r1] = v.w;
            int gr2 = gr + 64;
            float4 v2 = make_float4(0.f, 0.f, 0.f, 0.f);
            if (gr2 < N) v2 = *(const float4*)&X[(size_t)gr2 * 128 + kb + kq];
            Xs[kq + 0][r1 + 64] = v2.x; Xs[kq + 1][r1 + 64] = v2.y;
            Xs[kq + 2][r1 + 64] = v2.z; Xs[kq + 3][r1 + 64] = v2.w;
        }
        // stage W -------------------------------------------------------------
        *(float4*)&Ws[kk][c4]     = *(const float4*)&W[(size_t)(kb + kk) * 128 + c4];
        *(float4*)&Ws[kk + 8][c4] = *(const float4*)&W[(size_t)(kb + kk + 8) * 128 + c4];
        __syncthreads();
#pragma unroll
        for (int k = 0; k < 16; ++k) {
            float xf[8], wf[8];
            *(float4*)&xf[0] = *(const float4*)&Xs[k][tr];
            *(float4*)&xf[4] = *(const float4*)&Xs[k][tr + 4];
            *(float4*)&wf[0] = *(const float4*)&Ws[k][tc];
            *(float4*)&wf[4] = *(const float4*)&Ws[k][tc + 4];
#pragma unroll
            for (int i = 0; i < 8; ++i)
#pragma unroll
                for (int j = 0; j < 8; ++j) acc[i][j] = fmaf(xf[i], wf[j], acc[i][j]);
        }
        __syncthreads();
    }
#pragma unroll
    for (int i = 0; i < 8; ++i) {
        int gr = row0 + tr + i;
        if (gr < N) {
            float4 o0 = make_float4(acc[i][0], acc[i][1], acc[i][2], acc[i][3]);
            float4 o1 = make_float4(acc[i][4], acc[i][5], acc[i][6], acc[i][7]);
            *(float4*)&C[(size_t)gr * 128 + tc]     = o0;
            *(float4*)&C[(size_t)gr * 128 + tc + 4] = o1;
        }
    }
}

// ---- per-node softmax + aggregation ---------------------------------------
template <bool RELU>
__global__ void gat_aggregate_kernel(const float* __restrict__ hs,
                                     const float* __restrict__ al_s,
                                     const float* __restrict__ al_d,
                                     const int* __restrict__ row_ptr,
                                     const int* __restrict__ col,
                                     const float* __restrict__ bias,
                                     float* __restrict__ out, int N) {
    int node = (int)((blockIdx.x * (unsigned)blockDim.x + threadIdx.x) >> 6);
    int lane = threadIdx.x & 63;
    if (node >= N) return;
    int begin = row_ptr[node], end = row_ptr[node + 1];
    float ald = al_d[node];

    // phase 1: max logit
    float m = -INFINITY;
    for (int i = begin + lane; i < end; i += 64) {
        float l = al_s[col[i]] + ald;
        l = (l >= 0.f) ? l : 0.2f * l;
        m = fmaxf(m, l);
    }
    for (int o = 32; o >= 1; o >>= 1) m = fmaxf(m, __shfl_xor(m, o));

    // phase 2: denom
    float denom = 0.f;
    for (int i = begin + lane; i < end; i += 64) {
        float l = al_s[col[i]] + ald;
        l = (l >= 0.f) ? l : 0.2f * l;
        denom += __expf(l - m);
    }
    for (int o = 32; o >= 1; o >>= 1) denom += __shfl_xor(denom, o);
    float rden = (denom > 0.f) ? 1.f / denom : 0.f;

    // phase 3: weighted gather of hs rows (512B coalesced per edge)
    const int d0 = lane * 2;
    float a0 = 0.f, a1 = 0.f;
    for (int i = begin; i < end; ++i) {
        int s = col[i];                       // uniform across wave -> broadcast
        float l = al_s[s] + ald;
        l = (l >= 0.f) ? l : 0.2f * l;
        float alpha = __expf(l - m) * rden;
        float2 v = *(const float2*)&hs[(size_t)s * 128 + d0];
        a0 = fmaf(alpha, v.x, a0);
        a1 = fmaf(alpha, v.y, a1);
    }
    float o0 = a0 + bias[d0], o1 = a1 + bias[d0 + 1];
    if (RELU) { o0 = fmaxf(o0, 0.f); o1 = fmaxf(o1, 0.f); }
    *(float2*)&out[(size_t)node * 128 + d0] = make_float2(o0, o1);
}

// ---------------------------------------------------------------------------
extern "C" void kernel_launch(void* const* d_in, const int* in_sizes, int n_in,
                              void* d_out, int out_size, void* d_ws,
                              size_t ws_size, hipStream_t stream) {
    const float* x    = (const float*)d_in[0];
    const int*  eidx  = (const int*)d_in[1];
    const float* W1s  = (const float*)d_in[2];
    const float* W1d  = (const float*)d_in[3];
    const float* a1s  = (const float*)d_in[4];
    const float* a1d  = (const float*)d_in[5];
    const float* b1   = (const float*)d_in[6];
    const float* W2s  = (const float*)d_in[7];
    const float* W2d  = (const float*)d_in[8];
    const float* a2s  = (const float*)d_in[9];
    const float* a2d  = (const float*)d_in[10];
    const float* b2   = (const float*)d_in[11];

    const int N = in_sizes[0] / 128;
    const int E = in_sizes[1] / 2;
    const int* src = eidx;
    const int* dst = eidx + E;

    // workspace layout (256B aligned chunks)
    char* p = (char*)d_ws;
    auto alloc = [&](size_t bytes) {
        char* r = p;
        p += (bytes + 255) & ~(size_t)255;
        return r;
    };
    float* hsA    = (float*)alloc((size_t)N * 128 * 4);  // hs (layer1), hs2 (layer2)
    float* h1     = (float*)alloc((size_t)N * 128 * 4);  // layer-1 output
    int*   row_ptr= (int*)alloc((size_t)(N + 1) * 4);
    int*   nxt    = (int*)alloc((size_t)N * 4);          // counts, then cursors
    int*   col    = (int*)alloc((size_t)E * 4);
    float* al_s   = (float*)alloc((size_t)N * 4);
    float* al_d   = (float*)alloc((size_t)N * 4);
    float* wv1s   = (float*)alloc(128 * 4);
    float* wv1d   = (float*)alloc(128 * 4);
    float* wv2s   = (float*)alloc(128 * 4);
    float* wv2d   = (float*)alloc(128 * 4);
    int*   aux    = (int*)alloc(1024 * 4);

    const int nb = (N + 1023) / 1024;

    // attention weight vectors
    make_wv_kernel<<<1, 128, 0, stream>>>(W1s, a1s, wv1s);
    make_wv_kernel<<<1, 128, 0, stream>>>(W1d, a1d, wv1d);
    make_wv_kernel<<<1, 128, 0, stream>>>(W2s, a2s, wv2s);
    make_wv_kernel<<<1, 128, 0, stream>>>(W2d, a2d, wv2d);

    // CSR build (once, reused by both layers)
    hipMemsetAsync(nxt, 0, (size_t)N * 4, stream);
    hist_kernel<<<(E + 255) / 256, 256, 0, stream>>>(dst, nxt, E);
    scan1_kernel<<<nb, 1024, 0, stream>>>(nxt, row_ptr, aux, N);
    scan2_kernel<<<1, 64, 0, stream>>>(aux, nb);
    scan3_kernel<<<nb, 1024, 0, stream>>>(row_ptr, nxt, aux, N, E);
    scatter_kernel<<<(E + 255) / 256, 256, 0, stream>>>(src, dst, nxt, col, E);

    const int gemm_grid = (N + 127) / 128;
    const int wave_grid = (N + 3) / 4;  // 4 waves (nodes) per 256-thread block

    // ---- layer 1 ----
    gemm128_kernel<<<gemm_grid, 256, 0, stream>>>(x, W1s, hsA, N);
    compute_al_kernel<<<wave_grid, 256, 0, stream>>>(x, wv1s, wv1d, al_s, al_d, N);
    gat_aggregate_kernel<true><<<wave_grid, 256, 0, stream>>>(
        hsA, al_s, al_d, row_ptr, col, b1, h1, N);

    // ---- layer 2 ----
    gemm128_kernel<<<gemm_grid, 256, 0, stream>>>(h1, W2s, hsA, N);
    compute_al_kernel<<<wave_grid, 256, 0, stream>>>(h1, wv2s, wv2d, al_s, al_d, N);
    gat_aggregate_kernel<false><<<wave_grid, 256, 0, stream>>>(
        hsA, al_s, al_d, row_ptr, col, b2, (float*)d_out, N);
}

// Round 5
// 664.517 us; speedup vs baseline: 1.1261x; 1.1261x over previous
//
#include <hip/hip_runtime.h>
#include <hip/hip_bf16.h>
#include <math.h>

// ---------------------------------------------------------------------------
// 2-layer GAT (H=1, D=128) on MI355X.
// Per layer:  hs = x @ W_src            (SIMT f32 GEMM, 128-wide)
//             al_s[n] = x[n]·(W_src@a_src),  al_d[n] = x[n]·(W_dst@a_dst)
//             fused single-pass per-dst softmax-aggregate over in-edges
// CSR (by dst) built once on device, reused by both layers.
// Logits are tiny (|l| <~ 2) so exp() without max-subtraction is safe;
// alpha = exp(l)/sum exp(l) identical to reference up to rounding.
// ---------------------------------------------------------------------------

// ---- tiny: wv[k] = sum_d W[k*128+d] * a[d] --------------------------------
__global__ void make_wv_kernel(const float* __restrict__ W,
                               const float* __restrict__ a,
                               float* __restrict__ wv) {
    int k = threadIdx.x;  // 128 threads
    float s = 0.f;
    for (int d = 0; d < 128; ++d) s += W[k * 128 + d] * a[d];
    wv[k] = s;
}

// ---- al_s / al_d ----------------------------------------------------------
__global__ void compute_al_kernel(const float* __restrict__ X,
                                  const float* __restrict__ wsv,
                                  const float* __restrict__ wdv,
                                  float* __restrict__ al_s,
                                  float* __restrict__ al_d, int N) {
    int node = (int)((blockIdx.x * (unsigned)blockDim.x + threadIdx.x) >> 6);
    int lane = threadIdx.x & 63;
    if (node >= N) return;
    float2 xv = *(const float2*)&X[(size_t)node * 128 + lane * 2];
    float2 sv = *(const float2*)&wsv[lane * 2];
    float2 dv = *(const float2*)&wdv[lane * 2];
    float ps = xv.x * sv.x + xv.y * sv.y;
    float pd = xv.x * dv.x + xv.y * dv.y;
    for (int o = 32; o >= 1; o >>= 1) {
        ps += __shfl_xor(ps, o);
        pd += __shfl_xor(pd, o);
    }
    if (lane == 0) { al_s[node] = ps; al_d[node] = pd; }
}

// ---- CSR build ------------------------------------------------------------
__global__ void hist_kernel(const int* __restrict__ dst, int* __restrict__ cnt,
                            int E) {
    int i = blockIdx.x * blockDim.x + threadIdx.x;
    if (i < E) atomicAdd(&cnt[dst[i]], 1);
}

__global__ void scan1_kernel(const int* __restrict__ cnt, int* __restrict__ out,
                             int* __restrict__ aux, int N) {
    __shared__ int sh[1024];
    int i = blockIdx.x * 1024 + threadIdx.x;
    int v = (i < N) ? cnt[i] : 0;
    sh[threadIdx.x] = v;
    __syncthreads();
    for (int o = 1; o < 1024; o <<= 1) {
        int t = (threadIdx.x >= o) ? sh[threadIdx.x - o] : 0;
        __syncthreads();
        sh[threadIdx.x] += t;
        __syncthreads();
    }
    if (i < N) out[i] = sh[threadIdx.x] - v;  // exclusive
    if (threadIdx.x == 1023) aux[blockIdx.x] = sh[1023];
}

__global__ void scan2_kernel(int* __restrict__ aux, int nb) {
    if (blockIdx.x == 0 && threadIdx.x == 0) {
        int run = 0;
        for (int i = 0; i < nb; ++i) { int v = aux[i]; aux[i] = run; run += v; }
    }
}

__global__ void scan3_kernel(int* __restrict__ row_ptr, int* __restrict__ nxt,
                             const int* __restrict__ aux, int N, int E) {
    int i = blockIdx.x * 1024 + threadIdx.x;
    if (i < N) {
        int v = row_ptr[i] + aux[blockIdx.x];
        row_ptr[i] = v;
        nxt[i] = v;
    }
    if (i == 0) row_ptr[N] = E;
}

__global__ void scatter_kernel(const int* __restrict__ src,
                               const int* __restrict__ dst,
                               int* __restrict__ nxt, int* __restrict__ col,
                               int E) {
    int i = blockIdx.x * blockDim.x + threadIdx.x;
    if (i < E) {
        int p = atomicAdd(&nxt[dst[i]], 1);
        col[p] = src[i];
    }
}

// ---- GEMM: C[N,128] = X[N,128] @ W[128,128], f32 SIMT ---------------------
__global__ __launch_bounds__(256) void gemm128_kernel(
    const float* __restrict__ X, const float* __restrict__ W,
    float* __restrict__ C, int N) {
    __shared__ float Xs[16][132];
    __shared__ float Ws[16][132];
    const int tid = threadIdx.x;
    const int row0 = blockIdx.x * 128;
    const int rg = tid >> 4, cg = tid & 15;
    const int tr = rg * 8, tc = cg * 8;
    float acc[8][8];
#pragma unroll
    for (int i = 0; i < 8; ++i)
#pragma unroll
        for (int j = 0; j < 8; ++j) acc[i][j] = 0.f;

    const int r1 = tid >> 2;            // 0..63
    const int kq = (tid & 3) * 4;       // 0,4,8,12
    const int kk = tid >> 5;            // 0..7
    const int c4 = (tid & 31) * 4;      // 0..124

    for (int kb = 0; kb < 128; kb += 16) {
        // stage X (transposed) ------------------------------------------------
        {
            int gr = row0 + r1;
            float4 v = make_float4(0.f, 0.f, 0.f, 0.f);
            if (gr < N) v = *(const float4*)&X[(size_t)gr * 128 + kb + kq];
            Xs[kq + 0][r1] = v.x; Xs[kq + 1][r1] = v.y;
            Xs[kq + 2][r1] = v.z; Xs[kq + 3][r1] = v.w;
            int gr2 = gr + 64;
            float4 v2 = make_float4(0.f, 0.f, 0.f, 0.f);
            if (gr2 < N) v2 = *(const float4*)&X[(size_t)gr2 * 128 + kb + kq];
            Xs[kq + 0][r1 + 64] = v2.x; Xs[kq + 1][r1 + 64] = v2.y;
            Xs[kq + 2][r1 + 64] = v2.z; Xs[kq + 3][r1 + 64] = v2.w;
        }
        // stage W -------------------------------------------------------------
        *(float4*)&Ws[kk][c4]     = *(const float4*)&W[(size_t)(kb + kk) * 128 + c4];
        *(float4*)&Ws[kk + 8][c4] = *(const float4*)&W[(size_t)(kb + kk + 8) * 128 + c4];
        __syncthreads();
#pragma unroll
        for (int k = 0; k < 16; ++k) {
            float xf[8], wf[8];
            *(float4*)&xf[0] = *(const float4*)&Xs[k][tr];
            *(float4*)&xf[4] = *(const float4*)&Xs[k][tr + 4];
            *(float4*)&wf[0] = *(const float4*)&Ws[k][tc];
            *(float4*)&wf[4] = *(const float4*)&Ws[k][tc + 4];
#pragma unroll
            for (int i = 0; i < 8; ++i)
#pragma unroll
                for (int j = 0; j < 8; ++j) acc[i][j] = fmaf(xf[i], wf[j], acc[i][j]);
        }
        __syncthreads();
    }
#pragma unroll
    for (int i = 0; i < 8; ++i) {
        int gr = row0 + tr + i;
        if (gr < N) {
            float4 o0 = make_float4(acc[i][0], acc[i][1], acc[i][2], acc[i][3]);
            float4 o1 = make_float4(acc[i][4], acc[i][5], acc[i][6], acc[i][7]);
            *(float4*)&C[(size_t)gr * 128 + tc]     = o0;
            *(float4*)&C[(size_t)gr * 128 + tc + 4] = o1;
        }
    }
}

// ---- fused single-pass softmax + aggregation ------------------------------
// alpha_i = exp(l_i) / sum_j exp(l_j)  (logits small, no max needed)
// out[node] = (sum_i w_i * hs[src_i]) / (sum_i w_i) + bias
// col[i] is wave-uniform per iteration -> den identical in all lanes.
template <bool RELU>
__global__ __launch_bounds__(256) void gat_aggregate_fused(
    const float* __restrict__ hs, const float* __restrict__ al_s,
    const float* __restrict__ al_d, const int* __restrict__ row_ptr,
    const int* __restrict__ col, const float* __restrict__ bias,
    float* __restrict__ out, int N) {
    int node = (int)((blockIdx.x * 256u + threadIdx.x) >> 6);
    int lane = threadIdx.x & 63;
    if (node >= N) return;
    const int begin = row_ptr[node], end = row_ptr[node + 1];
    const float ald = al_d[node];
    const int d0 = lane * 2;

    float acc0 = 0.f, acc1 = 0.f, den = 0.f;
    for (int i = begin; i < end; i += 4) {
        int   idx[4];
        float w[4];
        float2 v[4];
#pragma unroll
        for (int j = 0; j < 4; ++j)
            idx[j] = (i + j < end) ? col[i + j] : -1;
#pragma unroll
        for (int j = 0; j < 4; ++j) {
            int s = (idx[j] >= 0) ? idx[j] : 0;
            v[j] = *(const float2*)&hs[(size_t)s * 128 + d0];
            float l = al_s[s] + ald;
            l = (l >= 0.f) ? l : 0.2f * l;
            w[j] = (idx[j] >= 0) ? __expf(l) : 0.f;
        }
#pragma unroll
        for (int j = 0; j < 4; ++j) {
            den  += w[j];
            acc0 = fmaf(w[j], v[j].x, acc0);
            acc1 = fmaf(w[j], v[j].y, acc1);
        }
    }
    const float rden = (den > 0.f) ? 1.f / den : 0.f;
    float o0 = acc0 * rden + bias[d0];
    float o1 = acc1 * rden + bias[d0 + 1];
    if (RELU) { o0 = fmaxf(o0, 0.f); o1 = fmaxf(o1, 0.f); }
    *(float2*)&out[(size_t)node * 128 + d0] = make_float2(o0, o1);
}

// ---------------------------------------------------------------------------
extern "C" void kernel_launch(void* const* d_in, const int* in_sizes, int n_in,
                              void* d_out, int out_size, void* d_ws,
                              size_t ws_size, hipStream_t stream) {
    const float* x    = (const float*)d_in[0];
    const int*  eidx  = (const int*)d_in[1];
    const float* W1s  = (const float*)d_in[2];
    const float* a1s  = (const float*)d_in[4];
    const float* W1d  = (const float*)d_in[3];
    const float* a1d  = (const float*)d_in[5];
    const float* b1   = (const float*)d_in[6];
    const float* W2s  = (const float*)d_in[7];
    const float* W2d  = (const float*)d_in[8];
    const float* a2s  = (const float*)d_in[9];
    const float* a2d  = (const float*)d_in[10];
    const float* b2   = (const float*)d_in[11];

    const int N = in_sizes[0] / 128;
    const int E = in_sizes[1] / 2;
    const int* src = eidx;
    const int* dst = eidx + E;

    // workspace layout (256B aligned chunks)
    char* p = (char*)d_ws;
    auto alloc = [&](size_t bytes) {
        char* r = p;
        p += (bytes + 255) & ~(size_t)255;
        return r;
    };
    float* hsA    = (float*)alloc((size_t)N * 128 * 4);  // hs (layer1), hs2 (layer2)
    float* h1     = (float*)alloc((size_t)N * 128 * 4);  // layer-1 output
    int*   row_ptr= (int*)alloc((size_t)(N + 1) * 4);
    int*   nxt    = (int*)alloc((size_t)N * 4);          // counts, then cursors
    int*   col    = (int*)alloc((size_t)E * 4);
    float* al_s   = (float*)alloc((size_t)N * 4);
    float* al_d   = (float*)alloc((size_t)N * 4);
    float* wv1s   = (float*)alloc(128 * 4);
    float* wv1d   = (float*)alloc(128 * 4);
    float* wv2s   = (float*)alloc(128 * 4);
    float* wv2d   = (float*)alloc(128 * 4);
    int*   aux    = (int*)alloc(1024 * 4);

    const int nb = (N + 1023) / 1024;

    // attention weight vectors
    make_wv_kernel<<<1, 128, 0, stream>>>(W1s, a1s, wv1s);
    make_wv_kernel<<<1, 128, 0, stream>>>(W1d, a1d, wv1d);
    make_wv_kernel<<<1, 128, 0, stream>>>(W2s, a2s, wv2s);
    make_wv_kernel<<<1, 128, 0, stream>>>(W2d, a2d, wv2d);

    // CSR build (once, reused by both layers)
    hipMemsetAsync(nxt, 0, (size_t)N * 4, stream);
    hist_kernel<<<(E + 255) / 256, 256, 0, stream>>>(dst, nxt, E);
    scan1_kernel<<<nb, 1024, 0, stream>>>(nxt, row_ptr, aux, N);
    scan2_kernel<<<1, 64, 0, stream>>>(aux, nb);
    scan3_kernel<<<nb, 1024, 0, stream>>>(row_ptr, nxt, aux, N, E);
    scatter_kernel<<<(E + 255) / 256, 256, 0, stream>>>(src, dst, nxt, col, E);

    const int gemm_grid = (N + 127) / 128;
    const int wave_grid = (N + 3) / 4;  // 4 waves (nodes) per 256-thread block

    // ---- layer 1 ----
    gemm128_kernel<<<gemm_grid, 256, 0, stream>>>(x, W1s, hsA, N);
    compute_al_kernel<<<wave_grid, 256, 0, stream>>>(x, wv1s, wv1d, al_s, al_d, N);
    gat_aggregate_fused<true><<<wave_grid, 256, 0, stream>>>(
        hsA, al_s, al_d, row_ptr, col, b1, h1, N);

    // ---- layer 2 ----
    gemm128_kernel<<<gemm_grid, 256, 0, stream>>>(h1, W2s, hsA, N);
    compute_al_kernel<<<wave_grid, 256, 0, stream>>>(h1, wv2s, wv2d, al_s, al_d, N);
    gat_aggregate_fused<false><<<wave_grid, 256, 0, stream>>>(
        hsA, al_s, al_d, row_ptr, col, b2, (float*)d_out, N);
}

// Round 6
// 587.966 us; speedup vs baseline: 1.2728x; 1.1302x over previous
//
#include <hip/hip_runtime.h>
#include <hip/hip_bf16.h>
#include <math.h>

// ---------------------------------------------------------------------------
// 2-layer GAT (H=1, D=128) on MI355X.
// Per layer:  hs = x @ W_src            (SIMT f32 GEMM, 128-wide)
//             al_s[n] = x[n]·(W_src@a_src),  al_d[n] = x[n]·(W_dst@a_dst)
//             fused single-pass per-dst softmax-aggregate over in-edges
// CSR (by dst) built once on device, reused by both layers.
// Aggregate: lane-parallel edge weights (col/al_s gather + exp 64-wide),
// then a pure register-fed gather loop with 8 hs-row loads in flight.
// ---------------------------------------------------------------------------

// ---- wv[b][k] = sum_d W_b[k*128+d] * a_b[d], b=0..3 -----------------------
__global__ void make_wv4_kernel(const float* __restrict__ W1s,
                                const float* __restrict__ a1s,
                                const float* __restrict__ W1d,
                                const float* __restrict__ a1d,
                                const float* __restrict__ W2s,
                                const float* __restrict__ a2s,
                                const float* __restrict__ W2d,
                                const float* __restrict__ a2d,
                                float* __restrict__ wv) {
    const float* Wt[4] = {W1s, W1d, W2s, W2d};
    const float* at[4] = {a1s, a1d, a2s, a2d};
    const float* W = Wt[blockIdx.x];
    const float* a = at[blockIdx.x];
    int k = threadIdx.x;  // 128 threads
    float s = 0.f;
    for (int d = 0; d < 128; ++d) s += W[k * 128 + d] * a[d];
    wv[blockIdx.x * 128 + k] = s;
}

// ---- al_s / al_d ----------------------------------------------------------
__global__ void compute_al_kernel(const float* __restrict__ X,
                                  const float* __restrict__ wsv,
                                  const float* __restrict__ wdv,
                                  float* __restrict__ al_s,
                                  float* __restrict__ al_d, int N) {
    int node = (int)((blockIdx.x * (unsigned)blockDim.x + threadIdx.x) >> 6);
    int lane = threadIdx.x & 63;
    if (node >= N) return;
    float2 xv = *(const float2*)&X[(size_t)node * 128 + lane * 2];
    float2 sv = *(const float2*)&wsv[lane * 2];
    float2 dv = *(const float2*)&wdv[lane * 2];
    float ps = xv.x * sv.x + xv.y * sv.y;
    float pd = xv.x * dv.x + xv.y * dv.y;
    for (int o = 32; o >= 1; o >>= 1) {
        ps += __shfl_xor(ps, o);
        pd += __shfl_xor(pd, o);
    }
    if (lane == 0) { al_s[node] = ps; al_d[node] = pd; }
}

// ---- CSR build ------------------------------------------------------------
__global__ void hist_kernel(const int* __restrict__ dst, int* __restrict__ cnt,
                            int E) {
    int i = blockIdx.x * blockDim.x + threadIdx.x;
    if (i < E) atomicAdd(&cnt[dst[i]], 1);
}

__global__ void scan1_kernel(const int* __restrict__ cnt, int* __restrict__ out,
                             int* __restrict__ aux, int N) {
    __shared__ int sh[1024];
    int i = blockIdx.x * 1024 + threadIdx.x;
    int v = (i < N) ? cnt[i] : 0;
    sh[threadIdx.x] = v;
    __syncthreads();
    for (int o = 1; o < 1024; o <<= 1) {
        int t = (threadIdx.x >= o) ? sh[threadIdx.x - o] : 0;
        __syncthreads();
        sh[threadIdx.x] += t;
        __syncthreads();
    }
    if (i < N) out[i] = sh[threadIdx.x] - v;  // exclusive
    if (threadIdx.x == 1023) aux[blockIdx.x] = sh[1023];
}

// parallel exclusive scan of aux[0..nb), nb <= 1024
__global__ void scan2_kernel(int* __restrict__ aux, int nb) {
    __shared__ int sh[1024];
    int t = threadIdx.x;
    int v = (t < nb) ? aux[t] : 0;
    sh[t] = v;
    __syncthreads();
    for (int o = 1; o < 1024; o <<= 1) {
        int u = (t >= o) ? sh[t - o] : 0;
        __syncthreads();
        sh[t] += u;
        __syncthreads();
    }
    if (t < nb) aux[t] = sh[t] - v;  // exclusive
}

__global__ void scan3_kernel(int* __restrict__ row_ptr, int* __restrict__ nxt,
                             const int* __restrict__ aux, int N, int E) {
    int i = blockIdx.x * 1024 + threadIdx.x;
    if (i < N) {
        int v = row_ptr[i] + aux[blockIdx.x];
        row_ptr[i] = v;
        nxt[i] = v;
    }
    if (i == 0) row_ptr[N] = E;
}

__global__ void scatter_kernel(const int* __restrict__ src,
                               const int* __restrict__ dst,
                               int* __restrict__ nxt, int* __restrict__ col,
                               int E) {
    int i = blockIdx.x * blockDim.x + threadIdx.x;
    if (i < E) {
        int p = atomicAdd(&nxt[dst[i]], 1);
        col[p] = src[i];
    }
}

// ---- GEMM: C[N,128] = X[N,128] @ W[128,128], f32 SIMT ---------------------
__global__ __launch_bounds__(256) void gemm128_kernel(
    const float* __restrict__ X, const float* __restrict__ W,
    float* __restrict__ C, int N) {
    __shared__ float Xs[16][132];
    __shared__ float Ws[16][132];
    const int tid = threadIdx.x;
    const int row0 = blockIdx.x * 128;
    const int rg = tid >> 4, cg = tid & 15;
    const int tr = rg * 8, tc = cg * 8;
    float acc[8][8];
#pragma unroll
    for (int i = 0; i < 8; ++i)
#pragma unroll
        for (int j = 0; j < 8; ++j) acc[i][j] = 0.f;

    const int r1 = tid >> 2;            // 0..63
    const int kq = (tid & 3) * 4;       // 0,4,8,12
    const int kk = tid >> 5;            // 0..7
    const int c4 = (tid & 31) * 4;      // 0..124

    for (int kb = 0; kb < 128; kb += 16) {
        // stage X (transposed)
        {
            int gr = row0 + r1;
            float4 v = make_float4(0.f, 0.f, 0.f, 0.f);
            if (gr < N) v = *(const float4*)&X[(size_t)gr * 128 + kb + kq];
            Xs[kq + 0][r1] = v.x; Xs[kq + 1][r1] = v.y;
            Xs[kq + 2][r1] = v.z; Xs[kq + 3][r1] = v.w;
            int gr2 = gr + 64;
            float4 v2 = make_float4(0.f, 0.f, 0.f, 0.f);
            if (gr2 < N) v2 = *(const float4*)&X[(size_t)gr2 * 128 + kb + kq];
            Xs[kq + 0][r1 + 64] = v2.x; Xs[kq + 1][r1 + 64] = v2.y;
            Xs[kq + 2][r1 + 64] = v2.z; Xs[kq + 3][r1 + 64] = v2.w;
        }
        // stage W
        *(float4*)&Ws[kk][c4]     = *(const float4*)&W[(size_t)(kb + kk) * 128 + c4];
        *(float4*)&Ws[kk + 8][c4] = *(const float4*)&W[(size_t)(kb + kk + 8) * 128 + c4];
        __syncthreads();
#pragma unroll
        for (int k = 0; k < 16; ++k) {
            float xf[8], wf[8];
            *(float4*)&xf[0] = *(const float4*)&Xs[k][tr];
            *(float4*)&xf[4] = *(const float4*)&Xs[k][tr + 4];
            *(float4*)&wf[0] = *(const float4*)&Ws[k][tc];
            *(float4*)&wf[4] = *(const float4*)&Ws[k][tc + 4];
#pragma unroll
            for (int i = 0; i < 8; ++i)
#pragma unroll
                for (int j = 0; j < 8; ++j) acc[i][j] = fmaf(xf[i], wf[j], acc[i][j]);
        }
        __syncthreads();
    }
#pragma unroll
    for (int i = 0; i < 8; ++i) {
        int gr = row0 + tr + i;
        if (gr < N) {
            float4 o0 = make_float4(acc[i][0], acc[i][1], acc[i][2], acc[i][3]);
            float4 o1 = make_float4(acc[i][4], acc[i][5], acc[i][6], acc[i][7]);
            *(float4*)&C[(size_t)gr * 128 + tc]     = o0;
            *(float4*)&C[(size_t)gr * 128 + tc + 4] = o1;
        }
    }
}

// ---- fused single-pass softmax + aggregation ------------------------------
// Per 64-edge chunk: lane e loads col[base+e], gathers al_s, computes
// w = exp(leaky(...)) in parallel; den via butterfly reduce. Gather loop is
// register-fed (shfl) -> 8 independent 512B hs loads in flight.
template <bool RELU>
__global__ __launch_bounds__(256) void gat_aggregate_fused(
    const float* __restrict__ hs, const float* __restrict__ al_s,
    const float* __restrict__ al_d, const int* __restrict__ row_ptr,
    const int* __restrict__ col, const float* __restrict__ bias,
    float* __restrict__ out, int N) {
    int node = (int)((blockIdx.x * 256u + threadIdx.x) >> 6);
    int lane = threadIdx.x & 63;
    if (node >= N) return;
    const int begin = row_ptr[node], end = row_ptr[node + 1];
    const float ald = al_d[node];
    const int d0 = lane * 2;

    float acc0 = 0.f, acc1 = 0.f, den = 0.f;
    for (int base = begin; base < end; base += 64) {
        const int cnt = min(64, end - base);
        int myidx = 0;
        float w = 0.f;
        if (lane < cnt) {
            myidx = col[base + lane];
            float l = al_s[myidx] + ald;
            l = (l >= 0.f) ? l : 0.2f * l;
            w = __expf(l);
        }
        float ws = w;
#pragma unroll
        for (int o = 32; o >= 1; o >>= 1) ws += __shfl_xor(ws, o);
        den += ws;  // uniform across lanes

        // e <= 56 since e < cnt <= 64 and e % 8 == 0  ->  e+j <= 63 (safe shfl)
        for (int e = 0; e < cnt; e += 8) {
            float2 v[8];
            float we[8];
#pragma unroll
            for (int j = 0; j < 8; ++j) {
                int s = __shfl(myidx, e + j);   // idx 0 for tail lanes
                we[j] = __shfl(w, e + j);       // 0 for tail lanes
                v[j] = *(const float2*)&hs[(size_t)s * 128 + d0];
            }
#pragma unroll
            for (int j = 0; j < 8; ++j) {
                acc0 = fmaf(we[j], v[j].x, acc0);
                acc1 = fmaf(we[j], v[j].y, acc1);
            }
        }
    }
    const float rden = (den > 0.f) ? 1.f / den : 0.f;
    float o0 = acc0 * rden + bias[d0];
    float o1 = acc1 * rden + bias[d0 + 1];
    if (RELU) { o0 = fmaxf(o0, 0.f); o1 = fmaxf(o1, 0.f); }
    *(float2*)&out[(size_t)node * 128 + d0] = make_float2(o0, o1);
}

// ---------------------------------------------------------------------------
extern "C" void kernel_launch(void* const* d_in, const int* in_sizes, int n_in,
                              void* d_out, int out_size, void* d_ws,
                              size_t ws_size, hipStream_t stream) {
    const float* x    = (const float*)d_in[0];
    const int*  eidx  = (const int*)d_in[1];
    const float* W1s  = (const float*)d_in[2];
    const float* W1d  = (const float*)d_in[3];
    const float* a1s  = (const float*)d_in[4];
    const float* a1d  = (const float*)d_in[5];
    const float* b1   = (const float*)d_in[6];
    const float* W2s  = (const float*)d_in[7];
    const float* W2d  = (const float*)d_in[8];
    const float* a2s  = (const float*)d_in[9];
    const float* a2d  = (const float*)d_in[10];
    const float* b2   = (const float*)d_in[11];

    const int N = in_sizes[0] / 128;
    const int E = in_sizes[1] / 2;
    const int* src = eidx;
    const int* dst = eidx + E;

    // workspace layout (256B aligned chunks)
    char* p = (char*)d_ws;
    auto alloc = [&](size_t bytes) {
        char* r = p;
        p += (bytes + 255) & ~(size_t)255;
        return r;
    };
    float* hsA    = (float*)alloc((size_t)N * 128 * 4);  // hs (layer1), hs2 (layer2)
    float* h1     = (float*)alloc((size_t)N * 128 * 4);  // layer-1 output
    int*   row_ptr= (int*)alloc((size_t)(N + 1) * 4);
    int*   nxt    = (int*)alloc((size_t)N * 4);          // counts, then cursors
    int*   col    = (int*)alloc((size_t)E * 4);
    float* al_s   = (float*)alloc((size_t)N * 4);
    float* al_d   = (float*)alloc((size_t)N * 4);
    float* wv     = (float*)alloc(4 * 128 * 4);          // wv1s|wv1d|wv2s|wv2d
    int*   aux    = (int*)alloc(1024 * 4);

    const int nb = (N + 1023) / 1024;

    // attention weight vectors (one launch, 4 blocks)
    make_wv4_kernel<<<4, 128, 0, stream>>>(W1s, a1s, W1d, a1d, W2s, a2s, W2d,
                                           a2d, wv);

    // CSR build (once, reused by both layers)
    hipMemsetAsync(nxt, 0, (size_t)N * 4, stream);
    hist_kernel<<<(E + 255) / 256, 256, 0, stream>>>(dst, nxt, E);
    scan1_kernel<<<nb, 1024, 0, stream>>>(nxt, row_ptr, aux, N);
    scan2_kernel<<<1, 1024, 0, stream>>>(aux, nb);
    scan3_kernel<<<nb, 1024, 0, stream>>>(row_ptr, nxt, aux, N, E);
    scatter_kernel<<<(E + 255) / 256, 256, 0, stream>>>(src, dst, nxt, col, E);

    const int gemm_grid = (N + 127) / 128;
    const int wave_grid = (N + 3) / 4;  // 4 waves (nodes) per 256-thread block

    // ---- layer 1 ----
    gemm128_kernel<<<gemm_grid, 256, 0, stream>>>(x, W1s, hsA, N);
    compute_al_kernel<<<wave_grid, 256, 0, stream>>>(x, wv + 0, wv + 128, al_s,
                                                     al_d, N);
    gat_aggregate_fused<true><<<wave_grid, 256, 0, stream>>>(
        hsA, al_s, al_d, row_ptr, col, b1, h1, N);

    // ---- layer 2 ----
    gemm128_kernel<<<gemm_grid, 256, 0, stream>>>(h1, W2s, hsA, N);
    compute_al_kernel<<<wave_grid, 256, 0, stream>>>(h1, wv + 256, wv + 384,
                                                     al_s, al_d, N);
    gat_aggregate_fused<false><<<wave_grid, 256, 0, stream>>>(
        hsA, al_s, al_d, row_ptr, col, b2, (float*)d_out, N);
}

// Round 7
// 554.209 us; speedup vs baseline: 1.3503x; 1.0609x over previous
//
#include <hip/hip_runtime.h>
#include <hip/hip_bf16.h>
#include <math.h>

// ---------------------------------------------------------------------------
// 2-layer GAT (H=1, D=128) on MI355X.
// Per layer:  hs = x @ W_src            (SIMT f32 GEMM, 128-wide)
//             al_s[n] = x[n]·(W_src@a_src),  al_d[n] = x[n]·(W_dst@a_dst)
//             fused single-pass per-dst softmax-aggregate over in-edges
// CSR (by dst) built once on device, reused by both layers.
// CSR build uses 8-edges-per-thread ILP: independent atomic+store chains
// overlap in the memory system (scatter was latency-bound at 1 chain/thread).
// ---------------------------------------------------------------------------

// ---- wv[b][k] = sum_d W_b[k*128+d] * a_b[d], b=0..3 -----------------------
__global__ void make_wv4_kernel(const float* __restrict__ W1s,
                                const float* __restrict__ a1s,
                                const float* __restrict__ W1d,
                                const float* __restrict__ a1d,
                                const float* __restrict__ W2s,
                                const float* __restrict__ a2s,
                                const float* __restrict__ W2d,
                                const float* __restrict__ a2d,
                                float* __restrict__ wv) {
    const float* Wt[4] = {W1s, W1d, W2s, W2d};
    const float* at[4] = {a1s, a1d, a2s, a2d};
    const float* W = Wt[blockIdx.x];
    const float* a = at[blockIdx.x];
    int k = threadIdx.x;  // 128 threads
    float s = 0.f;
    for (int d = 0; d < 128; ++d) s += W[k * 128 + d] * a[d];
    wv[blockIdx.x * 128 + k] = s;
}

// ---- al_s / al_d ----------------------------------------------------------
__global__ void compute_al_kernel(const float* __restrict__ X,
                                  const float* __restrict__ wsv,
                                  const float* __restrict__ wdv,
                                  float* __restrict__ al_s,
                                  float* __restrict__ al_d, int N) {
    int node = (int)((blockIdx.x * (unsigned)blockDim.x + threadIdx.x) >> 6);
    int lane = threadIdx.x & 63;
    if (node >= N) return;
    float2 xv = *(const float2*)&X[(size_t)node * 128 + lane * 2];
    float2 sv = *(const float2*)&wsv[lane * 2];
    float2 dv = *(const float2*)&wdv[lane * 2];
    float ps = xv.x * sv.x + xv.y * sv.y;
    float pd = xv.x * dv.x + xv.y * dv.y;
    for (int o = 32; o >= 1; o >>= 1) {
        ps += __shfl_xor(ps, o);
        pd += __shfl_xor(pd, o);
    }
    if (lane == 0) { al_s[node] = ps; al_d[node] = pd; }
}

// ---- CSR build ------------------------------------------------------------
// hist: 4 edges/thread, fire-and-forget atomics, loads hoisted.
__global__ void hist_kernel(const int* __restrict__ dst, int* __restrict__ cnt,
                            int E) {
    const int base = blockIdx.x * (256 * 4);
    const int t = threadIdx.x;
    int d[4];
    bool ok[4];
#pragma unroll
    for (int j = 0; j < 4; ++j) {
        int i = base + j * 256 + t;
        ok[j] = (i < E);
        d[j] = ok[j] ? dst[i] : 0;
    }
#pragma unroll
    for (int j = 0; j < 4; ++j)
        if (ok[j]) atomicAdd(&cnt[d[j]], 1);
}

__global__ void scan1_kernel(const int* __restrict__ cnt, int* __restrict__ out,
                             int* __restrict__ aux, int N) {
    __shared__ int sh[1024];
    int i = blockIdx.x * 1024 + threadIdx.x;
    int v = (i < N) ? cnt[i] : 0;
    sh[threadIdx.x] = v;
    __syncthreads();
    for (int o = 1; o < 1024; o <<= 1) {
        int t = (threadIdx.x >= o) ? sh[threadIdx.x - o] : 0;
        __syncthreads();
        sh[threadIdx.x] += t;
        __syncthreads();
    }
    if (i < N) out[i] = sh[threadIdx.x] - v;  // exclusive
    if (threadIdx.x == 1023) aux[blockIdx.x] = sh[1023];
}

// parallel exclusive scan of aux[0..nb), nb <= 1024
__global__ void scan2_kernel(int* __restrict__ aux, int nb) {
    __shared__ int sh[1024];
    int t = threadIdx.x;
    int v = (t < nb) ? aux[t] : 0;
    sh[t] = v;
    __syncthreads();
    for (int o = 1; o < 1024; o <<= 1) {
        int u = (t >= o) ? sh[t - o] : 0;
        __syncthreads();
        sh[t] += u;
        __syncthreads();
    }
    if (t < nb) aux[t] = sh[t] - v;  // exclusive
}

__global__ void scan3_kernel(int* __restrict__ row_ptr, int* __restrict__ nxt,
                             const int* __restrict__ aux, int N, int E) {
    int i = blockIdx.x * 1024 + threadIdx.x;
    if (i < N) {
        int v = row_ptr[i] + aux[blockIdx.x];
        row_ptr[i] = v;
        nxt[i] = v;
    }
    if (i == 0) row_ptr[N] = E;
}

// scatter: 8 edges/thread. Phase A: all loads; phase B: 8 independent
// atomics issue back-to-back; phase C: 8 scattered stores. ~16 outstanding
// memory ops per wave instead of ~2 (was latency-bound at 133us).
__global__ void scatter_kernel(const int* __restrict__ src,
                               const int* __restrict__ dst,
                               int* __restrict__ nxt, int* __restrict__ col,
                               int E) {
    const int base = blockIdx.x * (256 * 8);
    const int t = threadIdx.x;
    int d[8], s[8], p[8];
    bool ok[8];
#pragma unroll
    for (int j = 0; j < 8; ++j) {
        int i = base + j * 256 + t;
        ok[j] = (i < E);
        d[j] = ok[j] ? dst[i] : 0;
        s[j] = ok[j] ? src[i] : 0;
    }
#pragma unroll
    for (int j = 0; j < 8; ++j)
        if (ok[j]) p[j] = atomicAdd(&nxt[d[j]], 1);
#pragma unroll
    for (int j = 0; j < 8; ++j)
        if (ok[j]) col[p[j]] = s[j];
}

// ---- GEMM: C[N,128] = X[N,128] @ W[128,128], f32 SIMT ---------------------
__global__ __launch_bounds__(256) void gemm128_kernel(
    const float* __restrict__ X, const float* __restrict__ W,
    float* __restrict__ C, int N) {
    __shared__ float Xs[16][132];
    __shared__ float Ws[16][132];
    const int tid = threadIdx.x;
    const int row0 = blockIdx.x * 128;
    const int rg = tid >> 4, cg = tid & 15;
    const int tr = rg * 8, tc = cg * 8;
    float acc[8][8];
#pragma unroll
    for (int i = 0; i < 8; ++i)
#pragma unroll
        for (int j = 0; j < 8; ++j) acc[i][j] = 0.f;

    const int r1 = tid >> 2;            // 0..63
    const int kq = (tid & 3) * 4;       // 0,4,8,12
    const int kk = tid >> 5;            // 0..7
    const int c4 = (tid & 31) * 4;      // 0..124

    for (int kb = 0; kb < 128; kb += 16) {
        // stage X (transposed)
        {
            int gr = row0 + r1;
            float4 v = make_float4(0.f, 0.f, 0.f, 0.f);
            if (gr < N) v = *(const float4*)&X[(size_t)gr * 128 + kb + kq];
            Xs[kq + 0][r1] = v.x; Xs[kq + 1][r1] = v.y;
            Xs[kq + 2][r1] = v.z; Xs[kq + 3][r1] = v.w;
            int gr2 = gr + 64;
            float4 v2 = make_float4(0.f, 0.f, 0.f, 0.f);
            if (gr2 < N) v2 = *(const float4*)&X[(size_t)gr2 * 128 + kb + kq];
            Xs[kq + 0][r1 + 64] = v2.x; Xs[kq + 1][r1 + 64] = v2.y;
            Xs[kq + 2][r1 + 64] = v2.z; Xs[kq + 3][r1 + 64] = v2.w;
        }
        // stage W
        *(float4*)&Ws[kk][c4]     = *(const float4*)&W[(size_t)(kb + kk) * 128 + c4];
        *(float4*)&Ws[kk + 8][c4] = *(const float4*)&W[(size_t)(kb + kk + 8) * 128 + c4];
        __syncthreads();
#pragma unroll
        for (int k = 0; k < 16; ++k) {
            float xf[8], wf[8];
            *(float4*)&xf[0] = *(const float4*)&Xs[k][tr];
            *(float4*)&xf[4] = *(const float4*)&Xs[k][tr + 4];
            *(float4*)&wf[0] = *(const float4*)&Ws[k][tc];
            *(float4*)&wf[4] = *(const float4*)&Ws[k][tc + 4];
#pragma unroll
            for (int i = 0; i < 8; ++i)
#pragma unroll
                for (int j = 0; j < 8; ++j) acc[i][j] = fmaf(xf[i], wf[j], acc[i][j]);
        }
        __syncthreads();
    }
#pragma unroll
    for (int i = 0; i < 8; ++i) {
        int gr = row0 + tr + i;
        if (gr < N) {
            float4 o0 = make_float4(acc[i][0], acc[i][1], acc[i][2], acc[i][3]);
            float4 o1 = make_float4(acc[i][4], acc[i][5], acc[i][6], acc[i][7]);
            *(float4*)&C[(size_t)gr * 128 + tc]     = o0;
            *(float4*)&C[(size_t)gr * 128 + tc + 4] = o1;
        }
    }
}

// ---- fused single-pass softmax + aggregation ------------------------------
// Per 64-edge chunk: lane e loads col[base+e], gathers al_s, computes
// w = exp(leaky(...)) in parallel; den via butterfly reduce. Gather loop is
// register-fed (shfl) -> 8 independent 512B hs loads in flight.
template <bool RELU>
__global__ __launch_bounds__(256) void gat_aggregate_fused(
    const float* __restrict__ hs, const float* __restrict__ al_s,
    const float* __restrict__ al_d, const int* __restrict__ row_ptr,
    const int* __restrict__ col, const float* __restrict__ bias,
    float* __restrict__ out, int N) {
    int node = (int)((blockIdx.x * 256u + threadIdx.x) >> 6);
    int lane = threadIdx.x & 63;
    if (node >= N) return;
    const int begin = row_ptr[node], end = row_ptr[node + 1];
    const float ald = al_d[node];
    const int d0 = lane * 2;

    float acc0 = 0.f, acc1 = 0.f, den = 0.f;
    for (int base = begin; base < end; base += 64) {
        const int cnt = min(64, end - base);
        int myidx = 0;
        float w = 0.f;
        if (lane < cnt) {
            myidx = col[base + lane];
            float l = al_s[myidx] + ald;
            l = (l >= 0.f) ? l : 0.2f * l;
            w = __expf(l);
        }
        float ws = w;
#pragma unroll
        for (int o = 32; o >= 1; o >>= 1) ws += __shfl_xor(ws, o);
        den += ws;  // uniform across lanes

        for (int e = 0; e < cnt; e += 8) {
            float2 v[8];
            float we[8];
#pragma unroll
            for (int j = 0; j < 8; ++j) {
                int s = __shfl(myidx, e + j);   // idx 0 for tail lanes
                we[j] = __shfl(w, e + j);       // 0 for tail lanes
                v[j] = *(const float2*)&hs[(size_t)s * 128 + d0];
            }
#pragma unroll
            for (int j = 0; j < 8; ++j) {
                acc0 = fmaf(we[j], v[j].x, acc0);
                acc1 = fmaf(we[j], v[j].y, acc1);
            }
        }
    }
    const float rden = (den > 0.f) ? 1.f / den : 0.f;
    float o0 = acc0 * rden + bias[d0];
    float o1 = acc1 * rden + bias[d0 + 1];
    if (RELU) { o0 = fmaxf(o0, 0.f); o1 = fmaxf(o1, 0.f); }
    *(float2*)&out[(size_t)node * 128 + d0] = make_float2(o0, o1);
}

// ---------------------------------------------------------------------------
extern "C" void kernel_launch(void* const* d_in, const int* in_sizes, int n_in,
                              void* d_out, int out_size, void* d_ws,
                              size_t ws_size, hipStream_t stream) {
    const float* x    = (const float*)d_in[0];
    const int*  eidx  = (const int*)d_in[1];
    const float* W1s  = (const float*)d_in[2];
    const float* W1d  = (const float*)d_in[3];
    const float* a1s  = (const float*)d_in[4];
    const float* a1d  = (const float*)d_in[5];
    const float* b1   = (const float*)d_in[6];
    const float* W2s  = (const float*)d_in[7];
    const float* W2d  = (const float*)d_in[8];
    const float* a2s  = (const float*)d_in[9];
    const float* a2d  = (const float*)d_in[10];
    const float* b2   = (const float*)d_in[11];

    const int N = in_sizes[0] / 128;
    const int E = in_sizes[1] / 2;
    const int* src = eidx;
    const int* dst = eidx + E;

    // workspace layout (256B aligned chunks)
    char* p = (char*)d_ws;
    auto alloc = [&](size_t bytes) {
        char* r = p;
        p += (bytes + 255) & ~(size_t)255;
        return r;
    };
    float* hsA    = (float*)alloc((size_t)N * 128 * 4);  // hs (layer1), hs2 (layer2)
    float* h1     = (float*)alloc((size_t)N * 128 * 4);  // layer-1 output
    int*   row_ptr= (int*)alloc((size_t)(N + 1) * 4);
    int*   nxt    = (int*)alloc((size_t)N * 4);          // counts, then cursors
    int*   col    = (int*)alloc((size_t)E * 4);
    float* al_s   = (float*)alloc((size_t)N * 4);
    float* al_d   = (float*)alloc((size_t)N * 4);
    float* wv     = (float*)alloc(4 * 128 * 4);          // wv1s|wv1d|wv2s|wv2d
    int*   aux    = (int*)alloc(1024 * 4);

    const int nb = (N + 1023) / 1024;

    // attention weight vectors (one launch, 4 blocks)
    make_wv4_kernel<<<4, 128, 0, stream>>>(W1s, a1s, W1d, a1d, W2s, a2s, W2d,
                                           a2d, wv);

    // CSR build (once, reused by both layers)
    hipMemsetAsync(nxt, 0, (size_t)N * 4, stream);
    hist_kernel<<<(E + 1023) / 1024, 256, 0, stream>>>(dst, nxt, E);
    scan1_kernel<<<nb, 1024, 0, stream>>>(nxt, row_ptr, aux, N);
    scan2_kernel<<<1, 1024, 0, stream>>>(aux, nb);
    scan3_kernel<<<nb, 1024, 0, stream>>>(row_ptr, nxt, aux, N, E);
    scatter_kernel<<<(E + 2047) / 2048, 256, 0, stream>>>(src, dst, nxt, col, E);

    const int gemm_grid = (N + 127) / 128;
    const int wave_grid = (N + 3) / 4;  // 4 waves (nodes) per 256-thread block

    // ---- layer 1 ----
    gemm128_kernel<<<gemm_grid, 256, 0, stream>>>(x, W1s, hsA, N);
    compute_al_kernel<<<wave_grid, 256, 0, stream>>>(x, wv + 0, wv + 128, al_s,
                                                     al_d, N);
    gat_aggregate_fused<true><<<wave_grid, 256, 0, stream>>>(
        hsA, al_s, al_d, row_ptr, col, b1, h1, N);

    // ---- layer 2 ----
    gemm128_kernel<<<gemm_grid, 256, 0, stream>>>(h1, W2s, hsA, N);
    compute_al_kernel<<<wave_grid, 256, 0, stream>>>(h1, wv + 256, wv + 384,
                                                     al_s, al_d, N);
    gat_aggregate_fused<false><<<wave_grid, 256, 0, stream>>>(
        hsA, al_s, al_d, row_ptr, col, b2, (float*)d_out, N);
}

// Round 8
// 455.429 us; speedup vs baseline: 1.6431x; 1.2169x over previous
//
#include <hip/hip_runtime.h>
#include <hip/hip_bf16.h>
#include <hip/hip_fp16.h>
#include <math.h>

// ---------------------------------------------------------------------------
// 2-layer GAT (H=1, D=128) on MI355X.
// hs = x @ W_src stored as FP16 (halves gather traffic; attention logits
// al_s/al_d stay full f32 via the precontracted W@a vectors).
// Fused single-pass per-dst softmax-aggregate over CSR (built once).
// Scatter commits edges in 7 dst-range phases so col writes cluster in a
// ~1MB window (L2-resident, full-line writebacks) instead of thrashing.
// ---------------------------------------------------------------------------

// ---- wv[b][k] = sum_d W_b[k*128+d] * a_b[d], b=0..3 -----------------------
__global__ void make_wv4_kernel(const float* __restrict__ W1s,
                                const float* __restrict__ a1s,
                                const float* __restrict__ W1d,
                                const float* __restrict__ a1d,
                                const float* __restrict__ W2s,
                                const float* __restrict__ a2s,
                                const float* __restrict__ W2d,
                                const float* __restrict__ a2d,
                                float* __restrict__ wv) {
    const float* Wt[4] = {W1s, W1d, W2s, W2d};
    const float* at[4] = {a1s, a1d, a2s, a2d};
    const float* W = Wt[blockIdx.x];
    const float* a = at[blockIdx.x];
    int k = threadIdx.x;  // 128 threads
    float s = 0.f;
    for (int d = 0; d < 128; ++d) s += W[k * 128 + d] * a[d];
    wv[blockIdx.x * 128 + k] = s;
}

// ---- al_s / al_d ----------------------------------------------------------
__global__ void compute_al_kernel(const float* __restrict__ X,
                                  const float* __restrict__ wsv,
                                  const float* __restrict__ wdv,
                                  float* __restrict__ al_s,
                                  float* __restrict__ al_d, int N) {
    int node = (int)((blockIdx.x * (unsigned)blockDim.x + threadIdx.x) >> 6);
    int lane = threadIdx.x & 63;
    if (node >= N) return;
    float2 xv = *(const float2*)&X[(size_t)node * 128 + lane * 2];
    float2 sv = *(const float2*)&wsv[lane * 2];
    float2 dv = *(const float2*)&wdv[lane * 2];
    float ps = xv.x * sv.x + xv.y * sv.y;
    float pd = xv.x * dv.x + xv.y * dv.y;
    for (int o = 32; o >= 1; o >>= 1) {
        ps += __shfl_xor(ps, o);
        pd += __shfl_xor(pd, o);
    }
    if (lane == 0) { al_s[node] = ps; al_d[node] = pd; }
}

// ---- CSR build ------------------------------------------------------------
__global__ void hist_kernel(const int* __restrict__ dst, int* __restrict__ cnt,
                            int E) {
    const int base = blockIdx.x * (256 * 4);
    const int t = threadIdx.x;
    int d[4];
    bool ok[4];
#pragma unroll
    for (int j = 0; j < 4; ++j) {
        int i = base + j * 256 + t;
        ok[j] = (i < E);
        d[j] = ok[j] ? dst[i] : 0;
    }
#pragma unroll
    for (int j = 0; j < 4; ++j)
        if (ok[j]) atomicAdd(&cnt[d[j]], 1);
}

__global__ void scan1_kernel(const int* __restrict__ cnt, int* __restrict__ out,
                             int* __restrict__ aux, int N) {
    __shared__ int sh[1024];
    int i = blockIdx.x * 1024 + threadIdx.x;
    int v = (i < N) ? cnt[i] : 0;
    sh[threadIdx.x] = v;
    __syncthreads();
    for (int o = 1; o < 1024; o <<= 1) {
        int t = (threadIdx.x >= o) ? sh[threadIdx.x - o] : 0;
        __syncthreads();
        sh[threadIdx.x] += t;
        __syncthreads();
    }
    if (i < N) out[i] = sh[threadIdx.x] - v;  // exclusive
    if (threadIdx.x == 1023) aux[blockIdx.x] = sh[1023];
}

__global__ void scan2_kernel(int* __restrict__ aux, int nb) {
    __shared__ int sh[1024];
    int t = threadIdx.x;
    int v = (t < nb) ? aux[t] : 0;
    sh[t] = v;
    __syncthreads();
    for (int o = 1; o < 1024; o <<= 1) {
        int u = (t >= o) ? sh[t - o] : 0;
        __syncthreads();
        sh[t] += u;
        __syncthreads();
    }
    if (t < nb) aux[t] = sh[t] - v;  // exclusive
}

__global__ void scan3_kernel(int* __restrict__ row_ptr, int* __restrict__ nxt,
                             const int* __restrict__ aux, int N, int E) {
    int i = blockIdx.x * 1024 + threadIdx.x;
    if (i < N) {
        int v = row_ptr[i] + aux[blockIdx.x];
        row_ptr[i] = v;
        nxt[i] = v;
    }
    if (i == 0) row_ptr[N] = E;
}

// scatter in dst-range phases: edges held in registers; phase r commits only
// dst in [r*16384, (r+1)*16384) -> col writes cluster in ~1MB window.
__global__ void scatter_kernel(const int* __restrict__ src,
                               const int* __restrict__ dst,
                               int* __restrict__ nxt, int* __restrict__ col,
                               int E, int nr) {
    const int base = blockIdx.x * (256 * 8);
    const int t = threadIdx.x;
    int d[8], s[8];
    bool ok[8];
#pragma unroll
    for (int j = 0; j < 8; ++j) {
        int i = base + j * 256 + t;
        ok[j] = (i < E);
        d[j] = ok[j] ? dst[i] : 0;
        s[j] = ok[j] ? src[i] : 0;
    }
    for (int r = 0; r < nr; ++r) {
        int p[8];
        bool go[8];
#pragma unroll
        for (int j = 0; j < 8; ++j)
            go[j] = ok[j] && ((d[j] >> 14) == r);
#pragma unroll
        for (int j = 0; j < 8; ++j)
            if (go[j]) p[j] = atomicAdd(&nxt[d[j]], 1);
#pragma unroll
        for (int j = 0; j < 8; ++j)
            if (go[j]) col[p[j]] = s[j];
    }
}

// ---- GEMM: C[N,128] = X[N,128] @ W[128,128], f32 compute ------------------
// HALF_OUT: write fp16 (for hs); else f32.
template <bool HALF_OUT>
__global__ __launch_bounds__(256) void gemm128_kernel(
    const float* __restrict__ X, const float* __restrict__ W,
    void* __restrict__ Cv, int N) {
    __shared__ float Xs[16][132];
    __shared__ float Ws[16][132];
    const int tid = threadIdx.x;
    const int row0 = blockIdx.x * 128;
    const int rg = tid >> 4, cg = tid & 15;
    const int tr = rg * 8, tc = cg * 8;
    float acc[8][8];
#pragma unroll
    for (int i = 0; i < 8; ++i)
#pragma unroll
        for (int j = 0; j < 8; ++j) acc[i][j] = 0.f;

    const int r1 = tid >> 2;
    const int kq = (tid & 3) * 4;
    const int kk = tid >> 5;
    const int c4 = (tid & 31) * 4;

    for (int kb = 0; kb < 128; kb += 16) {
        {
            int gr = row0 + r1;
            float4 v = make_float4(0.f, 0.f, 0.f, 0.f);
            if (gr < N) v = *(const float4*)&X[(size_t)gr * 128 + kb + kq];
            Xs[kq + 0][r1] = v.x; Xs[kq + 1][r1] = v.y;
            Xs[kq + 2][r1] = v.z; Xs[kq + 3][r1] = v.w;
            int gr2 = gr + 64;
            float4 v2 = make_float4(0.f, 0.f, 0.f, 0.f);
            if (gr2 < N) v2 = *(const float4*)&X[(size_t)gr2 * 128 + kb + kq];
            Xs[kq + 0][r1 + 64] = v2.x; Xs[kq + 1][r1 + 64] = v2.y;
            Xs[kq + 2][r1 + 64] = v2.z; Xs[kq + 3][r1 + 64] = v2.w;
        }
        *(float4*)&Ws[kk][c4]     = *(const float4*)&W[(size_t)(kb + kk) * 128 + c4];
        *(float4*)&Ws[kk + 8][c4] = *(const float4*)&W[(size_t)(kb + kk + 8) * 128 + c4];
        __syncthreads();
#pragma unroll
        for (int k = 0; k < 16; ++k) {
            float xf[8], wf[8];
            *(float4*)&xf[0] = *(const float4*)&Xs[k][tr];
            *(float4*)&xf[4] = *(const float4*)&Xs[k][tr + 4];
            *(float4*)&wf[0] = *(const float4*)&Ws[k][tc];
            *(float4*)&wf[4] = *(const float4*)&Ws[k][tc + 4];
#pragma unroll
            for (int i = 0; i < 8; ++i)
#pragma unroll
                for (int j = 0; j < 8; ++j) acc[i][j] = fmaf(xf[i], wf[j], acc[i][j]);
        }
        __syncthreads();
    }
#pragma unroll
    for (int i = 0; i < 8; ++i) {
        int gr = row0 + tr + i;
        if (gr < N) {
            if (HALF_OUT) {
                __half2 h[4];
#pragma unroll
                for (int q = 0; q < 4; ++q) {
                    __half2 t2;
                    t2.x = __float2half_rn(acc[i][2 * q]);
                    t2.y = __float2half_rn(acc[i][2 * q + 1]);
                    h[q] = t2;
                }
                __half* C = (__half*)Cv;
                *(uint4*)&C[(size_t)gr * 128 + tc] =
                    *(const uint4*)&h[0];
            } else {
                float* C = (float*)Cv;
                float4 o0 = make_float4(acc[i][0], acc[i][1], acc[i][2], acc[i][3]);
                float4 o1 = make_float4(acc[i][4], acc[i][5], acc[i][6], acc[i][7]);
                *(float4*)&C[(size_t)gr * 128 + tc]     = o0;
                *(float4*)&C[(size_t)gr * 128 + tc + 4] = o1;
            }
        }
    }
}

// ---- fused single-pass softmax + aggregation (fp16 hs) --------------------
template <bool RELU>
__global__ __launch_bounds__(256) void gat_aggregate_fused(
    const __half* __restrict__ hs, const float* __restrict__ al_s,
    const float* __restrict__ al_d, const int* __restrict__ row_ptr,
    const int* __restrict__ col, const float* __restrict__ bias,
    float* __restrict__ out, int N) {
    int node = (int)((blockIdx.x * 256u + threadIdx.x) >> 6);
    int lane = threadIdx.x & 63;
    if (node >= N) return;
    const int begin = row_ptr[node], end = row_ptr[node + 1];
    const float ald = al_d[node];
    const int d0 = lane * 2;

    float acc0 = 0.f, acc1 = 0.f, den = 0.f;
    for (int base = begin; base < end; base += 64) {
        const int cnt = min(64, end - base);
        int myidx = 0;
        float w = 0.f;
        if (lane < cnt) {
            myidx = col[base + lane];
            float l = al_s[myidx] + ald;
            l = (l >= 0.f) ? l : 0.2f * l;
            w = __expf(l);
        }
        float ws = w;
#pragma unroll
        for (int o = 32; o >= 1; o >>= 1) ws += __shfl_xor(ws, o);
        den += ws;

        for (int e = 0; e < cnt; e += 8) {
            __half2 v[8];
            float we[8];
#pragma unroll
            for (int j = 0; j < 8; ++j) {
                int s = __shfl(myidx, e + j);
                we[j] = __shfl(w, e + j);
                v[j] = *(const __half2*)&hs[(size_t)s * 128 + d0];
            }
#pragma unroll
            for (int j = 0; j < 8; ++j) {
                acc0 = fmaf(we[j], __half2float(v[j].x), acc0);
                acc1 = fmaf(we[j], __half2float(v[j].y), acc1);
            }
        }
    }
    const float rden = (den > 0.f) ? 1.f / den : 0.f;
    float o0 = acc0 * rden + bias[d0];
    float o1 = acc1 * rden + bias[d0 + 1];
    if (RELU) { o0 = fmaxf(o0, 0.f); o1 = fmaxf(o1, 0.f); }
    *(float2*)&out[(size_t)node * 128 + d0] = make_float2(o0, o1);
}

// ---------------------------------------------------------------------------
extern "C" void kernel_launch(void* const* d_in, const int* in_sizes, int n_in,
                              void* d_out, int out_size, void* d_ws,
                              size_t ws_size, hipStream_t stream) {
    const float* x    = (const float*)d_in[0];
    const int*  eidx  = (const int*)d_in[1];
    const float* W1s  = (const float*)d_in[2];
    const float* W1d  = (const float*)d_in[3];
    const float* a1s  = (const float*)d_in[4];
    const float* a1d  = (const float*)d_in[5];
    const float* b1   = (const float*)d_in[6];
    const float* W2s  = (const float*)d_in[7];
    const float* W2d  = (const float*)d_in[8];
    const float* a2s  = (const float*)d_in[9];
    const float* a2d  = (const float*)d_in[10];
    const float* b2   = (const float*)d_in[11];

    const int N = in_sizes[0] / 128;
    const int E = in_sizes[1] / 2;
    const int* src = eidx;
    const int* dst = eidx + E;

    char* p = (char*)d_ws;
    auto alloc = [&](size_t bytes) {
        char* r = p;
        p += (bytes + 255) & ~(size_t)255;
        return r;
    };
    __half* hsA   = (__half*)alloc((size_t)N * 128 * 2);  // fp16 hs (both layers)
    float* h1     = (float*)alloc((size_t)N * 128 * 4);   // layer-1 output (f32)
    int*   row_ptr= (int*)alloc((size_t)(N + 1) * 4);
    int*   nxt    = (int*)alloc((size_t)N * 4);
    int*   col    = (int*)alloc((size_t)E * 4);
    float* al_s   = (float*)alloc((size_t)N * 4);
    float* al_d   = (float*)alloc((size_t)N * 4);
    float* wv     = (float*)alloc(4 * 128 * 4);
    int*   aux    = (int*)alloc(1024 * 4);

    const int nb = (N + 1023) / 1024;
    const int nr = (N + 16383) >> 14;  // dst-range phases for scatter

    make_wv4_kernel<<<4, 128, 0, stream>>>(W1s, a1s, W1d, a1d, W2s, a2s, W2d,
                                           a2d, wv);

    // CSR build (once, reused by both layers)
    hipMemsetAsync(nxt, 0, (size_t)N * 4, stream);
    hist_kernel<<<(E + 1023) / 1024, 256, 0, stream>>>(dst, nxt, E);
    scan1_kernel<<<nb, 1024, 0, stream>>>(nxt, row_ptr, aux, N);
    scan2_kernel<<<1, 1024, 0, stream>>>(aux, nb);
    scan3_kernel<<<nb, 1024, 0, stream>>>(row_ptr, nxt, aux, N, E);
    scatter_kernel<<<(E + 2047) / 2048, 256, 0, stream>>>(src, dst, nxt, col,
                                                          E, nr);

    const int gemm_grid = (N + 127) / 128;
    const int wave_grid = (N + 3) / 4;

    // ---- layer 1 ----
    gemm128_kernel<true><<<gemm_grid, 256, 0, stream>>>(x, W1s, hsA, N);
    compute_al_kernel<<<wave_grid, 256, 0, stream>>>(x, wv + 0, wv + 128, al_s,
                                                     al_d, N);
    gat_aggregate_fused<true><<<wave_grid, 256, 0, stream>>>(
        hsA, al_s, al_d, row_ptr, col, b1, h1, N);

    // ---- layer 2 ----
    gemm128_kernel<true><<<gemm_grid, 256, 0, stream>>>(h1, W2s, hsA, N);
    compute_al_kernel<<<wave_grid, 256, 0, stream>>>(h1, wv + 256, wv + 384,
                                                     al_s, al_d, N);
    gat_aggregate_fused<false><<<wave_grid, 256, 0, stream>>>(
        hsA, al_s, al_d, row_ptr, col, b2, (float*)d_out, N);
}

// Round 9
// 339.059 us; speedup vs baseline: 2.2071x; 1.3432x over previous
//
#include <hip/hip_runtime.h>
#include <hip/hip_bf16.h>
#include <hip/hip_fp16.h>
#include <math.h>

// ---------------------------------------------------------------------------
// 2-layer GAT (H=1, D=128) on MI355X.
// hs = x @ W_src stored FP16; logits al_s/al_d f32 via precontracted W@a.
// Fused single-pass per-dst softmax-aggregate over CSR.
// CSR built by a 2-level LDS bucket sort (no global atomics):
//   A: per-block LDS hist over 256-node buckets -> counts[block][bucket]
//   B3: per-bucket exclusive scan over blocks (+ totals)
//   B2: scan totals -> bucket bases
//   C: place (src,dst) into bucket-grouped arrays via LDS cursors
//   D: per-bucket row_ptr + col via LDS count/scan/cursor (L2-local writes)
// ---------------------------------------------------------------------------

#define BKT_SHIFT 8           // 256 nodes per bucket
#define MAX_NB 512            // supports N <= 131072
#define EPB 2048              // edges per block in passes A and C

// ---- wv[b][k] = sum_d W_b[k*128+d] * a_b[d], b=0..3 -----------------------
__global__ void make_wv4_kernel(const float* __restrict__ W1s,
                                const float* __restrict__ a1s,
                                const float* __restrict__ W1d,
                                const float* __restrict__ a1d,
                                const float* __restrict__ W2s,
                                const float* __restrict__ a2s,
                                const float* __restrict__ W2d,
                                const float* __restrict__ a2d,
                                float* __restrict__ wv) {
    const float* Wt[4] = {W1s, W1d, W2s, W2d};
    const float* at[4] = {a1s, a1d, a2s, a2d};
    const float* W = Wt[blockIdx.x];
    const float* a = at[blockIdx.x];
    int k = threadIdx.x;  // 128 threads
    float s = 0.f;
    for (int d = 0; d < 128; ++d) s += W[k * 128 + d] * a[d];
    wv[blockIdx.x * 128 + k] = s;
}

// ---- al_s / al_d ----------------------------------------------------------
__global__ void compute_al_kernel(const float* __restrict__ X,
                                  const float* __restrict__ wsv,
                                  const float* __restrict__ wdv,
                                  float* __restrict__ al_s,
                                  float* __restrict__ al_d, int N) {
    int node = (int)((blockIdx.x * (unsigned)blockDim.x + threadIdx.x) >> 6);
    int lane = threadIdx.x & 63;
    if (node >= N) return;
    float2 xv = *(const float2*)&X[(size_t)node * 128 + lane * 2];
    float2 sv = *(const float2*)&wsv[lane * 2];
    float2 dv = *(const float2*)&wdv[lane * 2];
    float ps = xv.x * sv.x + xv.y * sv.y;
    float pd = xv.x * dv.x + xv.y * dv.y;
    for (int o = 32; o >= 1; o >>= 1) {
        ps += __shfl_xor(ps, o);
        pd += __shfl_xor(pd, o);
    }
    if (lane == 0) { al_s[node] = ps; al_d[node] = pd; }
}

// ---- CSR build: pass A — per-block bucket histogram -----------------------
__global__ void bucket_count_kernel(const int* __restrict__ dst,
                                    int* __restrict__ counts, int E, int NB) {
    __shared__ int h[MAX_NB];
    for (int i = threadIdx.x; i < NB; i += 256) h[i] = 0;
    __syncthreads();
    const int base = blockIdx.x * EPB;
#pragma unroll
    for (int j = 0; j < EPB / 256; ++j) {
        int i = base + j * 256 + threadIdx.x;
        if (i < E) atomicAdd(&h[dst[i] >> BKT_SHIFT], 1);
    }
    __syncthreads();
    for (int i = threadIdx.x; i < NB; i += 256)
        counts[(size_t)blockIdx.x * NB + i] = h[i];
}

// ---- pass B3 — per-bucket exclusive scan over blocks + totals -------------
// block b scans counts[0..NBLK)[b]; NBLK <= 1024.
__global__ void bucket_prefix_kernel(int* __restrict__ counts,
                                     int* __restrict__ totals, int NBLK,
                                     int NB) {
    __shared__ int lsum[256];
    const int b = blockIdx.x;
    const int t = threadIdx.x;
    int v[4];
    const int base = t * 4;
#pragma unroll
    for (int k = 0; k < 4; ++k) {
        int blk = base + k;
        v[k] = (blk < NBLK) ? counts[(size_t)blk * NB + b] : 0;
    }
    int s = v[0] + v[1] + v[2] + v[3];
    lsum[t] = s;
    __syncthreads();
    for (int o = 1; o < 256; o <<= 1) {
        int u = (t >= o) ? lsum[t - o] : 0;
        __syncthreads();
        lsum[t] += u;
        __syncthreads();
    }
    int run = lsum[t] - s;  // exclusive prefix of this thread's chunk
#pragma unroll
    for (int k = 0; k < 4; ++k) {
        int blk = base + k;
        if (blk < NBLK) counts[(size_t)blk * NB + b] = run;
        run += v[k];
    }
    if (t == 255) totals[b] = lsum[255];
}

// ---- pass B2 — exclusive scan of bucket totals -> bucket bases ------------
__global__ void bucket_base_kernel(const int* __restrict__ totals,
                                   int* __restrict__ bbase, int NB) {
    __shared__ int sh[MAX_NB];
    int t = threadIdx.x;  // 512 threads
    int v = (t < NB) ? totals[t] : 0;
    sh[t] = v;
    __syncthreads();
    for (int o = 1; o < MAX_NB; o <<= 1) {
        int u = (t >= o) ? sh[t - o] : 0;
        __syncthreads();
        sh[t] += u;
        __syncthreads();
    }
    if (t < NB) bbase[t] = sh[t] - v;
}

// ---- pass C — place edges into bucket-grouped arrays ----------------------
__global__ void bucket_place_kernel(const int* __restrict__ src,
                                    const int* __restrict__ dst,
                                    const int* __restrict__ prefix,
                                    const int* __restrict__ bbase,
                                    int* __restrict__ bsrc,
                                    int* __restrict__ bdst, int E, int NB) {
    __shared__ int cur[MAX_NB];
    const int blk = blockIdx.x;
    for (int i = threadIdx.x; i < NB; i += 256)
        cur[i] = bbase[i] + prefix[(size_t)blk * NB + i];
    __syncthreads();
    const int base = blk * EPB;
#pragma unroll
    for (int j = 0; j < EPB / 256; ++j) {
        int i = base + j * 256 + threadIdx.x;
        if (i < E) {
            int d = dst[i], s = src[i];
            int p = atomicAdd(&cur[d >> BKT_SHIFT], 1);
            bsrc[p] = s;
            bdst[p] = d;
        }
    }
}

// ---- pass D — per-bucket row_ptr + col ------------------------------------
__global__ void bucket_csr_kernel(const int* __restrict__ bsrc,
                                  const int* __restrict__ bdst,
                                  const int* __restrict__ bbase,
                                  int* __restrict__ row_ptr,
                                  int* __restrict__ col, int N, int E,
                                  int NB) {
    __shared__ int cnt[256];
    __shared__ int cur[256];
    const int b = blockIdx.x;
    const int t = threadIdx.x;  // 256 threads
    const int node0 = b << BKT_SHIFT;
    const int s = bbase[b];
    const int e = (b + 1 < NB) ? bbase[b + 1] : E;
    cnt[t] = 0;
    __syncthreads();
    for (int i = s + t; i < e; i += 256) atomicAdd(&cnt[bdst[i] & 255], 1);
    __syncthreads();
    // exclusive scan of cnt
    int v = cnt[t];
    cur[t] = v;
    __syncthreads();
    for (int o = 1; o < 256; o <<= 1) {
        int u = (t >= o) ? cur[t - o] : 0;
        __syncthreads();
        cur[t] += u;
        __syncthreads();
    }
    int start = cur[t] - v;  // exclusive
    if (node0 + t < N) row_ptr[node0 + t] = s + start;
    __syncthreads();
    cur[t] = s + start;  // global cursor
    __syncthreads();
    for (int i = s + t; i < e; i += 256) {
        int d = bdst[i] & 255, sr = bsrc[i];
        int p = atomicAdd(&cur[d], 1);
        col[p] = sr;
    }
    if (b == 0 && t == 0) row_ptr[N] = E;
}

// ---- GEMM: C[N,128] = X[N,128] @ W[128,128], f32 compute ------------------
template <bool HALF_OUT>
__global__ __launch_bounds__(256) void gemm128_kernel(
    const float* __restrict__ X, const float* __restrict__ W,
    void* __restrict__ Cv, int N) {
    __shared__ float Xs[16][132];
    __shared__ float Ws[16][132];
    const int tid = threadIdx.x;
    const int row0 = blockIdx.x * 128;
    const int rg = tid >> 4, cg = tid & 15;
    const int tr = rg * 8, tc = cg * 8;
    float acc[8][8];
#pragma unroll
    for (int i = 0; i < 8; ++i)
#pragma unroll
        for (int j = 0; j < 8; ++j) acc[i][j] = 0.f;

    const int r1 = tid >> 2;
    const int kq = (tid & 3) * 4;
    const int kk = tid >> 5;
    const int c4 = (tid & 31) * 4;

    for (int kb = 0; kb < 128; kb += 16) {
        {
            int gr = row0 + r1;
            float4 v = make_float4(0.f, 0.f, 0.f, 0.f);
            if (gr < N) v = *(const float4*)&X[(size_t)gr * 128 + kb + kq];
            Xs[kq + 0][r1] = v.x; Xs[kq + 1][r1] = v.y;
            Xs[kq + 2][r1] = v.z; Xs[kq + 3][r1] = v.w;
            int gr2 = gr + 64;
            float4 v2 = make_float4(0.f, 0.f, 0.f, 0.f);
            if (gr2 < N) v2 = *(const float4*)&X[(size_t)gr2 * 128 + kb + kq];
            Xs[kq + 0][r1 + 64] = v2.x; Xs[kq + 1][r1 + 64] = v2.y;
            Xs[kq + 2][r1 + 64] = v2.z; Xs[kq + 3][r1 + 64] = v2.w;
        }
        *(float4*)&Ws[kk][c4]     = *(const float4*)&W[(size_t)(kb + kk) * 128 + c4];
        *(float4*)&Ws[kk + 8][c4] = *(const float4*)&W[(size_t)(kb + kk + 8) * 128 + c4];
        __syncthreads();
#pragma unroll
        for (int k = 0; k < 16; ++k) {
            float xf[8], wf[8];
            *(float4*)&xf[0] = *(const float4*)&Xs[k][tr];
            *(float4*)&xf[4] = *(const float4*)&Xs[k][tr + 4];
            *(float4*)&wf[0] = *(const float4*)&Ws[k][tc];
            *(float4*)&wf[4] = *(const float4*)&Ws[k][tc + 4];
#pragma unroll
            for (int i = 0; i < 8; ++i)
#pragma unroll
                for (int j = 0; j < 8; ++j) acc[i][j] = fmaf(xf[i], wf[j], acc[i][j]);
        }
        __syncthreads();
    }
#pragma unroll
    for (int i = 0; i < 8; ++i) {
        int gr = row0 + tr + i;
        if (gr < N) {
            if (HALF_OUT) {
                __half2 h[4];
#pragma unroll
                for (int q = 0; q < 4; ++q) {
                    __half2 t2;
                    t2.x = __float2half_rn(acc[i][2 * q]);
                    t2.y = __float2half_rn(acc[i][2 * q + 1]);
                    h[q] = t2;
                }
                __half* C = (__half*)Cv;
                *(uint4*)&C[(size_t)gr * 128 + tc] = *(const uint4*)&h[0];
            } else {
                float* C = (float*)Cv;
                float4 o0 = make_float4(acc[i][0], acc[i][1], acc[i][2], acc[i][3]);
                float4 o1 = make_float4(acc[i][4], acc[i][5], acc[i][6], acc[i][7]);
                *(float4*)&C[(size_t)gr * 128 + tc]     = o0;
                *(float4*)&C[(size_t)gr * 128 + tc + 4] = o1;
            }
        }
    }
}

// ---- fused single-pass softmax + aggregation (fp16 hs) --------------------
template <bool RELU>
__global__ __launch_bounds__(256) void gat_aggregate_fused(
    const __half* __restrict__ hs, const float* __restrict__ al_s,
    const float* __restrict__ al_d, const int* __restrict__ row_ptr,
    const int* __restrict__ col, const float* __restrict__ bias,
    float* __restrict__ out, int N) {
    int node = (int)((blockIdx.x * 256u + threadIdx.x) >> 6);
    int lane = threadIdx.x & 63;
    if (node >= N) return;
    const int begin = row_ptr[node], end = row_ptr[node + 1];
    const float ald = al_d[node];
    const int d0 = lane * 2;

    float acc0 = 0.f, acc1 = 0.f, den = 0.f;
    for (int base = begin; base < end; base += 64) {
        const int cnt = min(64, end - base);
        int myidx = 0;
        float w = 0.f;
        if (lane < cnt) {
            myidx = col[base + lane];
            float l = al_s[myidx] + ald;
            l = (l >= 0.f) ? l : 0.2f * l;
            w = __expf(l);
        }
        float ws = w;
#pragma unroll
        for (int o = 32; o >= 1; o >>= 1) ws += __shfl_xor(ws, o);
        den += ws;

        for (int e = 0; e < cnt; e += 8) {
            __half2 v[8];
            float we[8];
#pragma unroll
            for (int j = 0; j < 8; ++j) {
                int s = __shfl(myidx, e + j);
                we[j] = __shfl(w, e + j);
                v[j] = *(const __half2*)&hs[(size_t)s * 128 + d0];
            }
#pragma unroll
            for (int j = 0; j < 8; ++j) {
                acc0 = fmaf(we[j], __half2float(v[j].x), acc0);
                acc1 = fmaf(we[j], __half2float(v[j].y), acc1);
            }
        }
    }
    const float rden = (den > 0.f) ? 1.f / den : 0.f;
    float o0 = acc0 * rden + bias[d0];
    float o1 = acc1 * rden + bias[d0 + 1];
    if (RELU) { o0 = fmaxf(o0, 0.f); o1 = fmaxf(o1, 0.f); }
    *(float2*)&out[(size_t)node * 128 + d0] = make_float2(o0, o1);
}

// ---------------------------------------------------------------------------
extern "C" void kernel_launch(void* const* d_in, const int* in_sizes, int n_in,
                              void* d_out, int out_size, void* d_ws,
                              size_t ws_size, hipStream_t stream) {
    const float* x    = (const float*)d_in[0];
    const int*  eidx  = (const int*)d_in[1];
    const float* W1s  = (const float*)d_in[2];
    const float* W1d  = (const float*)d_in[3];
    const float* a1s  = (const float*)d_in[4];
    const float* a1d  = (const float*)d_in[5];
    const float* b1   = (const float*)d_in[6];
    const float* W2s  = (const float*)d_in[7];
    const float* W2d  = (const float*)d_in[8];
    const float* a2s  = (const float*)d_in[9];
    const float* a2d  = (const float*)d_in[10];
    const float* b2   = (const float*)d_in[11];

    const int N = in_sizes[0] / 128;
    const int E = in_sizes[1] / 2;
    const int* src = eidx;
    const int* dst = eidx + E;

    const int NB   = (N + 255) >> BKT_SHIFT;   // buckets (<=512)
    const int NBLK = (E + EPB - 1) / EPB;      // edge blocks (<=1024)

    char* p = (char*)d_ws;
    auto alloc = [&](size_t bytes) {
        char* r = p;
        p += (bytes + 255) & ~(size_t)255;
        return r;
    };
    __half* hsA   = (__half*)alloc((size_t)N * 128 * 2);
    float* h1     = (float*)alloc((size_t)N * 128 * 4);
    int*   row_ptr= (int*)alloc((size_t)(N + 1) * 4);
    int*   col    = (int*)alloc((size_t)E * 4);
    int*   bsrc   = (int*)alloc((size_t)E * 4);
    int*   bdst   = (int*)alloc((size_t)E * 4);
    int*   counts = (int*)alloc((size_t)NBLK * NB * 4);
    int*   totals = (int*)alloc(MAX_NB * 4);
    int*   bbase  = (int*)alloc(MAX_NB * 4);
    float* al_s   = (float*)alloc((size_t)N * 4);
    float* al_d   = (float*)alloc((size_t)N * 4);
    float* wv     = (float*)alloc(4 * 128 * 4);

    make_wv4_kernel<<<4, 128, 0, stream>>>(W1s, a1s, W1d, a1d, W2s, a2s, W2d,
                                           a2d, wv);

    // CSR build (2-level LDS bucket sort; no global atomics)
    bucket_count_kernel<<<NBLK, 256, 0, stream>>>(dst, counts, E, NB);
    bucket_prefix_kernel<<<NB, 256, 0, stream>>>(counts, totals, NBLK, NB);
    bucket_base_kernel<<<1, MAX_NB, 0, stream>>>(totals, bbase, NB);
    bucket_place_kernel<<<NBLK, 256, 0, stream>>>(src, dst, counts, bbase,
                                                  bsrc, bdst, E, NB);
    bucket_csr_kernel<<<NB, 256, 0, stream>>>(bsrc, bdst, bbase, row_ptr, col,
                                              N, E, NB);

    const int gemm_grid = (N + 127) / 128;
    const int wave_grid = (N + 3) / 4;

    // ---- layer 1 ----
    gemm128_kernel<true><<<gemm_grid, 256, 0, stream>>>(x, W1s, hsA, N);
    compute_al_kernel<<<wave_grid, 256, 0, stream>>>(x, wv + 0, wv + 128, al_s,
                                                     al_d, N);
    gat_aggregate_fused<true><<<wave_grid, 256, 0, stream>>>(
        hsA, al_s, al_d, row_ptr, col, b1, h1, N);

    // ---- layer 2 ----
    gemm128_kernel<true><<<gemm_grid, 256, 0, stream>>>(h1, W2s, hsA, N);
    compute_al_kernel<<<wave_grid, 256, 0, stream>>>(h1, wv + 256, wv + 384,
                                                     al_s, al_d, N);
    gat_aggregate_fused<false><<<wave_grid, 256, 0, stream>>>(
        hsA, al_s, al_d, row_ptr, col, b2, (float*)d_out, N);
}

// Round 10
// 289.380 us; speedup vs baseline: 2.5860x; 1.1717x over previous
//
#include <hip/hip_runtime.h>
#include <hip/hip_bf16.h>
#include <hip/hip_fp16.h>
#include <math.h>
#include <type_traits>

// ---------------------------------------------------------------------------
// 2-layer GAT (H=1, D=128) on MI355X.
// hs = x @ W_src via fp16 MFMA (16x16x32), stored fp16.
// h1 (layer-1 out) stored fp16. Logits al_s/al_d f32 via precontracted W@a.
// Fused single-pass per-dst softmax-aggregate: 4 edges in flight per wave
// (16 lanes x 8 dims each), (idx,w) pairs broadcast from LDS.
// CSR built by 2-level LDS bucket sort (no global atomics).
// ---------------------------------------------------------------------------

#define BKT_SHIFT 8
#define MAX_NB 512
#define EPB 2048

typedef _Float16 half8 __attribute__((ext_vector_type(8)));
typedef float floatx4 __attribute__((ext_vector_type(4)));

// ---- W (f32 [k][c]) -> WT (fp16 [c][k]) -----------------------------------
__global__ void convert_w_kernel(const float* __restrict__ W1,
                                 const float* __restrict__ W2,
                                 __half* __restrict__ wt1,
                                 __half* __restrict__ wt2) {
    const float* W = (blockIdx.x >> 4) ? W2 : W1;
    __half* WT = (blockIdx.x >> 4) ? wt2 : wt1;
    const int sub = blockIdx.x & 15;
    const int k0 = (sub >> 2) * 32, c0 = (sub & 3) * 32;
    __shared__ float t[32][33];
    const int r = threadIdx.x >> 5, c = threadIdx.x & 31;
    for (int rr = r; rr < 32; rr += 8)
        t[rr][c] = W[(size_t)(k0 + rr) * 128 + c0 + c];
    __syncthreads();
    for (int rr = r; rr < 32; rr += 8)
        WT[(size_t)(c0 + rr) * 128 + k0 + c] = __float2half_rn(t[c][rr]);
}

// ---- wv[b][k] = sum_d W_b[k*128+d] * a_b[d], b=0..3 -----------------------
__global__ void make_wv4_kernel(const float* __restrict__ W1s,
                                const float* __restrict__ a1s,
                                const float* __restrict__ W1d,
                                const float* __restrict__ a1d,
                                const float* __restrict__ W2s,
                                const float* __restrict__ a2s,
                                const float* __restrict__ W2d,
                                const float* __restrict__ a2d,
                                float* __restrict__ wv) {
    const float* Wt[4] = {W1s, W1d, W2s, W2d};
    const float* at[4] = {a1s, a1d, a2s, a2d};
    const float* W = Wt[blockIdx.x];
    const float* a = at[blockIdx.x];
    int k = threadIdx.x;
    float s = 0.f;
    for (int d = 0; d < 128; ++d) s += W[k * 128 + d] * a[d];
    wv[blockIdx.x * 128 + k] = s;
}

// ---- al_s / al_d (templated input type) -----------------------------------
template <typename InT>
__global__ void compute_al_kernel(const InT* __restrict__ X,
                                  const float* __restrict__ wsv,
                                  const float* __restrict__ wdv,
                                  float* __restrict__ al_s,
                                  float* __restrict__ al_d, int N) {
    int node = (int)((blockIdx.x * (unsigned)blockDim.x + threadIdx.x) >> 6);
    int lane = threadIdx.x & 63;
    if (node >= N) return;
    float2 xv;
    if constexpr (std::is_same<InT, float>::value) {
        xv = *(const float2*)&X[(size_t)node * 128 + lane * 2];
    } else {
        xv = __half22float2(*(const __half2*)&X[(size_t)node * 128 + lane * 2]);
    }
    float2 sv = *(const float2*)&wsv[lane * 2];
    float2 dv = *(const float2*)&wdv[lane * 2];
    float ps = xv.x * sv.x + xv.y * sv.y;
    float pd = xv.x * dv.x + xv.y * dv.y;
    for (int o = 32; o >= 1; o >>= 1) {
        ps += __shfl_xor(ps, o);
        pd += __shfl_xor(pd, o);
    }
    if (lane == 0) { al_s[node] = ps; al_d[node] = pd; }
}

// ---- CSR build (unchanged bucket sort) ------------------------------------
__global__ void bucket_count_kernel(const int* __restrict__ dst,
                                    int* __restrict__ counts, int E, int NB) {
    __shared__ int h[MAX_NB];
    for (int i = threadIdx.x; i < NB; i += 256) h[i] = 0;
    __syncthreads();
    const int base = blockIdx.x * EPB;
#pragma unroll
    for (int j = 0; j < EPB / 256; ++j) {
        int i = base + j * 256 + threadIdx.x;
        if (i < E) atomicAdd(&h[dst[i] >> BKT_SHIFT], 1);
    }
    __syncthreads();
    for (int i = threadIdx.x; i < NB; i += 256)
        counts[(size_t)blockIdx.x * NB + i] = h[i];
}

__global__ void bucket_prefix_kernel(int* __restrict__ counts,
                                     int* __restrict__ totals, int NBLK,
                                     int NB) {
    __shared__ int lsum[256];
    const int b = blockIdx.x;
    const int t = threadIdx.x;
    int v[4];
    const int base = t * 4;
#pragma unroll
    for (int k = 0; k < 4; ++k) {
        int blk = base + k;
        v[k] = (blk < NBLK) ? counts[(size_t)blk * NB + b] : 0;
    }
    int s = v[0] + v[1] + v[2] + v[3];
    lsum[t] = s;
    __syncthreads();
    for (int o = 1; o < 256; o <<= 1) {
        int u = (t >= o) ? lsum[t - o] : 0;
        __syncthreads();
        lsum[t] += u;
        __syncthreads();
    }
    int run = lsum[t] - s;
#pragma unroll
    for (int k = 0; k < 4; ++k) {
        int blk = base + k;
        if (blk < NBLK) counts[(size_t)blk * NB + b] = run;
        run += v[k];
    }
    if (t == 255) totals[b] = lsum[255];
}

__global__ void bucket_base_kernel(const int* __restrict__ totals,
                                   int* __restrict__ bbase, int NB) {
    __shared__ int sh[MAX_NB];
    int t = threadIdx.x;
    int v = (t < NB) ? totals[t] : 0;
    sh[t] = v;
    __syncthreads();
    for (int o = 1; o < MAX_NB; o <<= 1) {
        int u = (t >= o) ? sh[t - o] : 0;
        __syncthreads();
        sh[t] += u;
        __syncthreads();
    }
    if (t < NB) bbase[t] = sh[t] - v;
}

__global__ void bucket_place_kernel(const int* __restrict__ src,
                                    const int* __restrict__ dst,
                                    const int* __restrict__ prefix,
                                    const int* __restrict__ bbase,
                                    int* __restrict__ bsrc,
                                    int* __restrict__ bdst, int E, int NB) {
    __shared__ int cur[MAX_NB];
    const int blk = blockIdx.x;
    for (int i = threadIdx.x; i < NB; i += 256)
        cur[i] = bbase[i] + prefix[(size_t)blk * NB + i];
    __syncthreads();
    const int base = blk * EPB;
#pragma unroll
    for (int j = 0; j < EPB / 256; ++j) {
        int i = base + j * 256 + threadIdx.x;
        if (i < E) {
            int d = dst[i], s = src[i];
            int p = atomicAdd(&cur[d >> BKT_SHIFT], 1);
            bsrc[p] = s;
            bdst[p] = d;
        }
    }
}

__global__ void bucket_csr_kernel(const int* __restrict__ bsrc,
                                  const int* __restrict__ bdst,
                                  const int* __restrict__ bbase,
                                  int* __restrict__ row_ptr,
                                  int* __restrict__ col, int N, int E,
                                  int NB) {
    __shared__ int cnt[256];
    __shared__ int cur[256];
    const int b = blockIdx.x;
    const int t = threadIdx.x;
    const int node0 = b << BKT_SHIFT;
    const int s = bbase[b];
    const int e = (b + 1 < NB) ? bbase[b + 1] : E;
    cnt[t] = 0;
    __syncthreads();
    for (int i = s + t; i < e; i += 256) atomicAdd(&cnt[bdst[i] & 255], 1);
    __syncthreads();
    int v = cnt[t];
    cur[t] = v;
    __syncthreads();
    for (int o = 1; o < 256; o <<= 1) {
        int u = (t >= o) ? cur[t - o] : 0;
        __syncthreads();
        cur[t] += u;
        __syncthreads();
    }
    int start = cur[t] - v;
    if (node0 + t < N) row_ptr[node0 + t] = s + start;
    __syncthreads();
    cur[t] = s + start;
    __syncthreads();
    for (int i = s + t; i < e; i += 256) {
        int d = bdst[i] & 255, sr = bsrc[i];
        int p = atomicAdd(&cur[d], 1);
        col[p] = sr;
    }
    if (b == 0 && t == 0) row_ptr[N] = E;
}

// ---- MFMA GEMM: C[N,128](fp16) = X[N,128] @ W  (WT fp16 [c][k]) -----------
// Block: 256 thr (4 waves), tile 64 rows x 128 cols, K=128 staged whole.
// A frag: lane holds X[row=(l&15)][k=(l>>4)*8+i]; B: W[k=(l>>4)*8+i][col=l&15]
// D: row=(l>>4)*4+r, col=l&15  (m89-verified layout).
template <typename InT>
__global__ __launch_bounds__(256) void gemm_mfma_kernel(
    const InT* __restrict__ X, const __half* __restrict__ WT,
    __half* __restrict__ C, int N) {
    __shared__ __align__(16) __half Ws[128][136];
    __shared__ __align__(16) __half Xs[64][136];
    const int tid = threadIdx.x;
    const int row0 = blockIdx.x * 64;

    // stage WT (fp16 [c][k], linear)
    {
        int cr = tid >> 1, off = (tid & 1) * 64;
        const __half* srcp = &WT[(size_t)cr * 128 + off];
#pragma unroll
        for (int q = 0; q < 8; ++q)
            *(float4*)&Ws[cr][off + q * 8] = *(const float4*)&srcp[q * 8];
    }
    // stage X rows (convert f32->fp16 if needed)
    {
        int xr = tid >> 2, co = (tid & 3) * 32;
        int gr = row0 + xr;
        if constexpr (std::is_same<InT, float>::value) {
#pragma unroll
            for (int q = 0; q < 4; ++q) {
                float4 lo = make_float4(0.f, 0.f, 0.f, 0.f);
                float4 hi = make_float4(0.f, 0.f, 0.f, 0.f);
                if (gr < N) {
                    lo = *(const float4*)&X[(size_t)gr * 128 + co + q * 8];
                    hi = *(const float4*)&X[(size_t)gr * 128 + co + q * 8 + 4];
                }
                __align__(16) __half2 tmp[4];
                tmp[0] = __floats2half2_rn(lo.x, lo.y);
                tmp[1] = __floats2half2_rn(lo.z, lo.w);
                tmp[2] = __floats2half2_rn(hi.x, hi.y);
                tmp[3] = __floats2half2_rn(hi.z, hi.w);
                *(float4*)&Xs[xr][co + q * 8] = *(const float4*)tmp;
            }
        } else {
#pragma unroll
            for (int q = 0; q < 4; ++q) {
                float4 vz = make_float4(0.f, 0.f, 0.f, 0.f);
                if (gr < N)
                    vz = *(const float4*)&X[(size_t)gr * 128 + co + q * 8];
                *(float4*)&Xs[xr][co + q * 8] = vz;
            }
        }
    }
    __syncthreads();

    const int wid = tid >> 6;
    const int lane = tid & 63;
    const int lr = lane & 15, ks = lane >> 4;
    floatx4 acc[8];
#pragma unroll
    for (int t = 0; t < 8; ++t) acc[t] = (floatx4){0.f, 0.f, 0.f, 0.f};

#pragma unroll
    for (int kk = 0; kk < 4; ++kk) {
        half8 a = *(const half8*)&Xs[wid * 16 + lr][kk * 32 + ks * 8];
#pragma unroll
        for (int t = 0; t < 8; ++t) {
            half8 b = *(const half8*)&Ws[t * 16 + lr][kk * 32 + ks * 8];
            acc[t] = __builtin_amdgcn_mfma_f32_16x16x32_f16(a, b, acc[t], 0, 0, 0);
        }
    }
#pragma unroll
    for (int r = 0; r < 4; ++r) {
        int grow = row0 + wid * 16 + ks * 4 + r;
        if (grow < N) {
#pragma unroll
            for (int t = 0; t < 8; ++t)
                C[(size_t)grow * 128 + t * 16 + lr] = __float2half_rn(acc[t][r]);
        }
    }
}

// ---- fused aggregate: 16 lanes x 8 dims, 4 edges per group ----------------
template <typename OutT, bool RELU>
__global__ __launch_bounds__(256) void gat_aggregate_fused(
    const __half* __restrict__ hs, const float* __restrict__ al_s,
    const float* __restrict__ al_d, const int* __restrict__ row_ptr,
    const int* __restrict__ col, const float* __restrict__ bias,
    OutT* __restrict__ out, int N) {
    __shared__ int2 pairs[4][64];
    const int wid = threadIdx.x >> 6;
    int node = (int)((blockIdx.x * 256u + threadIdx.x) >> 6);
    int lane = threadIdx.x & 63;
    if (node >= N) return;
    const int begin = row_ptr[node], end = row_ptr[node + 1];
    const float ald = al_d[node];
    const int dblk = (lane & 15) * 8;  // this lane's 8 dims
    const int slot = lane >> 4;        // edge slot within group of 4

    float acc[8] = {0.f, 0.f, 0.f, 0.f, 0.f, 0.f, 0.f, 0.f};
    float den = 0.f;

    for (int base = begin; base < end; base += 64) {
        const int cnt = min(64, end - base);
        int idx = 0;
        float w = 0.f;
        if (lane < cnt) {
            idx = col[base + lane];
            float l = al_s[idx] + ald;
            l = (l >= 0.f) ? l : 0.2f * l;
            w = __expf(l);
        }
        float ws = w;
#pragma unroll
        for (int o = 32; o >= 1; o >>= 1) ws += __shfl_xor(ws, o);
        den += ws;
        pairs[wid][lane] = make_int2(idx, __float_as_int(w));

        const int ng = (cnt + 3) >> 2;
        int g = 0;
        for (; g + 4 <= ng; g += 4) {
            int2 pr[4];
            float4 raw[4];
#pragma unroll
            for (int u = 0; u < 4; ++u) pr[u] = pairs[wid][(g + u) * 4 + slot];
#pragma unroll
            for (int u = 0; u < 4; ++u)
                raw[u] = *(const float4*)&hs[((unsigned)pr[u].x << 7) + dblk];
#pragma unroll
            for (int u = 0; u < 4; ++u) {
                float wu = __int_as_float(pr[u].y);
                const __half2* hp = (const __half2*)&raw[u];
#pragma unroll
                for (int q = 0; q < 4; ++q) {
                    float2 f = __half22float2(hp[q]);
                    acc[2 * q]     = fmaf(wu, f.x, acc[2 * q]);
                    acc[2 * q + 1] = fmaf(wu, f.y, acc[2 * q + 1]);
                }
            }
        }
        for (; g < ng; ++g) {
            int2 pr = pairs[wid][g * 4 + slot];
            float4 raw = *(const float4*)&hs[((unsigned)pr.x << 7) + dblk];
            float wu = __int_as_float(pr.y);
            const __half2* hp = (const __half2*)&raw;
#pragma unroll
            for (int q = 0; q < 4; ++q) {
                float2 f = __half22float2(hp[q]);
                acc[2 * q]     = fmaf(wu, f.x, acc[2 * q]);
                acc[2 * q + 1] = fmaf(wu, f.y, acc[2 * q + 1]);
            }
        }
    }
    // reduce across the 4 slots
#pragma unroll
    for (int r = 0; r < 8; ++r) {
        acc[r] += __shfl_xor(acc[r], 16);
        acc[r] += __shfl_xor(acc[r], 32);
    }
    if (slot == 0) {
        const float rden = (den > 0.f) ? 1.f / den : 0.f;
        float4 b0 = *(const float4*)&bias[dblk];
        float4 b1 = *(const float4*)&bias[dblk + 4];
        float o[8];
        o[0] = acc[0] * rden + b0.x; o[1] = acc[1] * rden + b0.y;
        o[2] = acc[2] * rden + b0.z; o[3] = acc[3] * rden + b0.w;
        o[4] = acc[4] * rden + b1.x; o[5] = acc[5] * rden + b1.y;
        o[6] = acc[6] * rden + b1.z; o[7] = acc[7] * rden + b1.w;
        if (RELU) {
#pragma unroll
            for (int r = 0; r < 8; ++r) o[r] = fmaxf(o[r], 0.f);
        }
        if constexpr (std::is_same<OutT, __half>::value) {
            __align__(16) __half2 hh[4];
#pragma unroll
            for (int q = 0; q < 4; ++q)
                hh[q] = __floats2half2_rn(o[2 * q], o[2 * q + 1]);
            *(float4*)&out[(size_t)node * 128 + dblk] = *(const float4*)hh;
        } else {
            *(float4*)&out[(size_t)node * 128 + dblk] =
                make_float4(o[0], o[1], o[2], o[3]);
            *(float4*)&out[(size_t)node * 128 + dblk + 4] =
                make_float4(o[4], o[5], o[6], o[7]);
        }
    }
}

// ---------------------------------------------------------------------------
extern "C" void kernel_launch(void* const* d_in, const int* in_sizes, int n_in,
                              void* d_out, int out_size, void* d_ws,
                              size_t ws_size, hipStream_t stream) {
    const float* x    = (const float*)d_in[0];
    const int*  eidx  = (const int*)d_in[1];
    const float* W1s  = (const float*)d_in[2];
    const float* W1d  = (const float*)d_in[3];
    const float* a1s  = (const float*)d_in[4];
    const float* a1d  = (const float*)d_in[5];
    const float* b1   = (const float*)d_in[6];
    const float* W2s  = (const float*)d_in[7];
    const float* W2d  = (const float*)d_in[8];
    const float* a2s  = (const float*)d_in[9];
    const float* a2d  = (const float*)d_in[10];
    const float* b2   = (const float*)d_in[11];

    const int N = in_sizes[0] / 128;
    const int E = in_sizes[1] / 2;
    const int* src = eidx;
    const int* dst = eidx + E;

    const int NB   = (N + 255) >> BKT_SHIFT;
    const int NBLK = (E + EPB - 1) / EPB;

    char* p = (char*)d_ws;
    auto alloc = [&](size_t bytes) {
        char* r = p;
        p += (bytes + 255) & ~(size_t)255;
        return r;
    };
    __half* hsA   = (__half*)alloc((size_t)N * 128 * 2);
    __half* h1    = (__half*)alloc((size_t)N * 128 * 2);
    int*   row_ptr= (int*)alloc((size_t)(N + 1) * 4);
    int*   col    = (int*)alloc((size_t)E * 4);
    int*   bsrc   = (int*)alloc((size_t)E * 4);
    int*   bdst   = (int*)alloc((size_t)E * 4);
    int*   counts = (int*)alloc((size_t)NBLK * NB * 4);
    int*   totals = (int*)alloc(MAX_NB * 4);
    int*   bbase  = (int*)alloc(MAX_NB * 4);
    float* al_s   = (float*)alloc((size_t)N * 4);
    float* al_d   = (float*)alloc((size_t)N * 4);
    float* wv     = (float*)alloc(4 * 128 * 4);
    __half* wt1   = (__half*)alloc(128 * 128 * 2);
    __half* wt2   = (__half*)alloc(128 * 128 * 2);

    convert_w_kernel<<<32, 256, 0, stream>>>(W1s, W2s, wt1, wt2);
    make_wv4_kernel<<<4, 128, 0, stream>>>(W1s, a1s, W1d, a1d, W2s, a2s, W2d,
                                           a2d, wv);

    bucket_count_kernel<<<NBLK, 256, 0, stream>>>(dst, counts, E, NB);
    bucket_prefix_kernel<<<NB, 256, 0, stream>>>(counts, totals, NBLK, NB);
    bucket_base_kernel<<<1, MAX_NB, 0, stream>>>(totals, bbase, NB);
    bucket_place_kernel<<<NBLK, 256, 0, stream>>>(src, dst, counts, bbase,
                                                  bsrc, bdst, E, NB);
    bucket_csr_kernel<<<NB, 256, 0, stream>>>(bsrc, bdst, bbase, row_ptr, col,
                                              N, E, NB);

    const int gemm_grid = (N + 63) / 64;
    const int wave_grid = (N + 3) / 4;

    // ---- layer 1 ----
    gemm_mfma_kernel<float><<<gemm_grid, 256, 0, stream>>>(x, wt1, hsA, N);
    compute_al_kernel<float><<<wave_grid, 256, 0, stream>>>(
        x, wv + 0, wv + 128, al_s, al_d, N);
    gat_aggregate_fused<__half, true><<<wave_grid, 256, 0, stream>>>(
        hsA, al_s, al_d, row_ptr, col, b1, h1, N);

    // ---- layer 2 ----
    gemm_mfma_kernel<__half><<<gemm_grid, 256, 0, stream>>>(h1, wt2, hsA, N);
    compute_al_kernel<__half><<<wave_grid, 256, 0, stream>>>(
        h1, wv + 256, wv + 384, al_s, al_d, N);
    gat_aggregate_fused<float, false><<<wave_grid, 256, 0, stream>>>(
        hsA, al_s, al_d, row_ptr, col, b2, (float*)d_out, N);
}

// Round 11
// 262.186 us; speedup vs baseline: 2.8542x; 1.1037x over previous
//
#include <hip/hip_runtime.h>
#include <hip/hip_bf16.h>
#include <hip/hip_fp16.h>
#include <math.h>
#include <type_traits>

// ---------------------------------------------------------------------------
// 2-layer GAT (H=1, D=128) on MI355X.
// hs = x @ W_src via fp16 MFMA (16x16x32), stored fp16. h1 fp16.
// Logits al_s/al_d f32 via precontracted W@a (wv vectors).
// Aggregate (r9-proven): 1 wave/node, 64-lane weight phase, shfl-broadcast
// register-fed gather with 8 half2 row-loads in flight.
// CSR by 2-level LDS bucket sort; pass C packs (dst&255)<<17|src in ONE int.
// ---------------------------------------------------------------------------

#define BKT_SHIFT 8
#define MAX_NB 512
#define EPB 2048

typedef _Float16 half8 __attribute__((ext_vector_type(8)));
typedef float floatx4 __attribute__((ext_vector_type(4)));

// ---- W (f32 [k][c]) -> WT (fp16 [c][k]) -----------------------------------
__global__ void convert_w_kernel(const float* __restrict__ W1,
                                 const float* __restrict__ W2,
                                 __half* __restrict__ wt1,
                                 __half* __restrict__ wt2) {
    const float* W = (blockIdx.x >> 4) ? W2 : W1;
    __half* WT = (blockIdx.x >> 4) ? wt2 : wt1;
    const int sub = blockIdx.x & 15;
    const int k0 = (sub >> 2) * 32, c0 = (sub & 3) * 32;
    __shared__ float t[32][33];
    const int r = threadIdx.x >> 5, c = threadIdx.x & 31;
    for (int rr = r; rr < 32; rr += 8)
        t[rr][c] = W[(size_t)(k0 + rr) * 128 + c0 + c];
    __syncthreads();
    for (int rr = r; rr < 32; rr += 8)
        WT[(size_t)(c0 + rr) * 128 + k0 + c] = __float2half_rn(t[c][rr]);
}

// ---- wv[b][k] = sum_d W_b[k*128+d] * a_b[d], b=0..3 -----------------------
__global__ void make_wv4_kernel(const float* __restrict__ W1s,
                                const float* __restrict__ a1s,
                                const float* __restrict__ W1d,
                                const float* __restrict__ a1d,
                                const float* __restrict__ W2s,
                                const float* __restrict__ a2s,
                                const float* __restrict__ W2d,
                                const float* __restrict__ a2d,
                                float* __restrict__ wv) {
    const float* Wt[4] = {W1s, W1d, W2s, W2d};
    const float* at[4] = {a1s, a1d, a2s, a2d};
    const float* W = Wt[blockIdx.x];
    const float* a = at[blockIdx.x];
    int k = threadIdx.x;
    float s = 0.f;
    for (int d = 0; d < 128; ++d) s += W[k * 128 + d] * a[d];
    wv[blockIdx.x * 128 + k] = s;
}

// ---- al_s / al_d ----------------------------------------------------------
template <typename InT>
__global__ void compute_al_kernel(const InT* __restrict__ X,
                                  const float* __restrict__ wsv,
                                  const float* __restrict__ wdv,
                                  float* __restrict__ al_s,
                                  float* __restrict__ al_d, int N) {
    int node = (int)((blockIdx.x * (unsigned)blockDim.x + threadIdx.x) >> 6);
    int lane = threadIdx.x & 63;
    if (node >= N) return;
    float2 xv;
    if constexpr (std::is_same<InT, float>::value) {
        xv = *(const float2*)&X[(size_t)node * 128 + lane * 2];
    } else {
        xv = __half22float2(*(const __half2*)&X[(size_t)node * 128 + lane * 2]);
    }
    float2 sv = *(const float2*)&wsv[lane * 2];
    float2 dv = *(const float2*)&wdv[lane * 2];
    float ps = xv.x * sv.x + xv.y * sv.y;
    float pd = xv.x * dv.x + xv.y * dv.y;
    for (int o = 32; o >= 1; o >>= 1) {
        ps += __shfl_xor(ps, o);
        pd += __shfl_xor(pd, o);
    }
    if (lane == 0) { al_s[node] = ps; al_d[node] = pd; }
}

// ---- CSR build ------------------------------------------------------------
__global__ void bucket_count_kernel(const int* __restrict__ dst,
                                    int* __restrict__ counts, int E, int NB) {
    __shared__ int h[MAX_NB];
    for (int i = threadIdx.x; i < NB; i += 256) h[i] = 0;
    __syncthreads();
    const int base = blockIdx.x * EPB;
#pragma unroll
    for (int j = 0; j < EPB / 256; ++j) {
        int i = base + j * 256 + threadIdx.x;
        if (i < E) atomicAdd(&h[dst[i] >> BKT_SHIFT], 1);
    }
    __syncthreads();
    for (int i = threadIdx.x; i < NB; i += 256)
        counts[(size_t)blockIdx.x * NB + i] = h[i];
}

__global__ void bucket_prefix_kernel(int* __restrict__ counts,
                                     int* __restrict__ totals, int NBLK,
                                     int NB) {
    __shared__ int lsum[256];
    const int b = blockIdx.x;
    const int t = threadIdx.x;
    int v[4];
    const int base = t * 4;
#pragma unroll
    for (int k = 0; k < 4; ++k) {
        int blk = base + k;
        v[k] = (blk < NBLK) ? counts[(size_t)blk * NB + b] : 0;
    }
    int s = v[0] + v[1] + v[2] + v[3];
    lsum[t] = s;
    __syncthreads();
    for (int o = 1; o < 256; o <<= 1) {
        int u = (t >= o) ? lsum[t - o] : 0;
        __syncthreads();
        lsum[t] += u;
        __syncthreads();
    }
    int run = lsum[t] - s;
#pragma unroll
    for (int k = 0; k < 4; ++k) {
        int blk = base + k;
        if (blk < NBLK) counts[(size_t)blk * NB + b] = run;
        run += v[k];
    }
    if (t == 255) totals[b] = lsum[255];
}

__global__ void bucket_base_kernel(const int* __restrict__ totals,
                                   int* __restrict__ bbase, int NB) {
    __shared__ int sh[MAX_NB];
    int t = threadIdx.x;
    int v = (t < NB) ? totals[t] : 0;
    sh[t] = v;
    __syncthreads();
    for (int o = 1; o < MAX_NB; o <<= 1) {
        int u = (t >= o) ? sh[t - o] : 0;
        __syncthreads();
        sh[t] += u;
        __syncthreads();
    }
    if (t < NB) bbase[t] = sh[t] - v;
}

// pass C: pack (dst&255)<<17 | src into ONE int -> 4B/edge windowed writes.
__global__ void bucket_place_kernel(const int* __restrict__ src,
                                    const int* __restrict__ dst,
                                    const int* __restrict__ prefix,
                                    const int* __restrict__ bbase,
                                    int* __restrict__ bpack, int E, int NB) {
    __shared__ int cur[MAX_NB];
    const int blk = blockIdx.x;
    for (int i = threadIdx.x; i < NB; i += 256)
        cur[i] = bbase[i] + prefix[(size_t)blk * NB + i];
    __syncthreads();
    const int base = blk * EPB;
#pragma unroll
    for (int j = 0; j < EPB / 256; ++j) {
        int i = base + j * 256 + threadIdx.x;
        if (i < E) {
            int d = dst[i], s = src[i];
            int p = atomicAdd(&cur[d >> BKT_SHIFT], 1);
            bpack[p] = ((d & 255) << 17) | s;
        }
    }
}

__global__ void bucket_csr_kernel(const int* __restrict__ bpack,
                                  const int* __restrict__ bbase,
                                  int* __restrict__ row_ptr,
                                  int* __restrict__ col, int N, int E,
                                  int NB) {
    __shared__ int cnt[256];
    __shared__ int cur[256];
    const int b = blockIdx.x;
    const int t = threadIdx.x;
    const int node0 = b << BKT_SHIFT;
    const int s = bbase[b];
    const int e = (b + 1 < NB) ? bbase[b + 1] : E;
    cnt[t] = 0;
    __syncthreads();
    for (int i = s + t; i < e; i += 256) atomicAdd(&cnt[bpack[i] >> 17], 1);
    __syncthreads();
    int v = cnt[t];
    cur[t] = v;
    __syncthreads();
    for (int o = 1; o < 256; o <<= 1) {
        int u = (t >= o) ? cur[t - o] : 0;
        __syncthreads();
        cur[t] += u;
        __syncthreads();
    }
    int start = cur[t] - v;
    if (node0 + t < N) row_ptr[node0 + t] = s + start;
    __syncthreads();
    cur[t] = s + start;
    __syncthreads();
    for (int i = s + t; i < e; i += 256) {
        int pk = bpack[i];
        int p = atomicAdd(&cur[pk >> 17], 1);
        col[p] = pk & 0x1FFFF;
    }
    if (b == 0 && t == 0) row_ptr[N] = E;
}

// ---- MFMA GEMM: C[N,128](fp16) = X[N,128] @ W  (WT fp16 [c][k]) -----------
template <typename InT>
__global__ __launch_bounds__(256) void gemm_mfma_kernel(
    const InT* __restrict__ X, const __half* __restrict__ WT,
    __half* __restrict__ C, int N) {
    __shared__ __align__(16) __half Ws[128][136];
    __shared__ __align__(16) __half Xs[64][136];
    const int tid = threadIdx.x;
    const int row0 = blockIdx.x * 64;

    {
        int cr = tid >> 1, off = (tid & 1) * 64;
        const __half* srcp = &WT[(size_t)cr * 128 + off];
#pragma unroll
        for (int q = 0; q < 8; ++q)
            *(float4*)&Ws[cr][off + q * 8] = *(const float4*)&srcp[q * 8];
    }
    {
        int xr = tid >> 2, co = (tid & 3) * 32;
        int gr = row0 + xr;
        if constexpr (std::is_same<InT, float>::value) {
#pragma unroll
            for (int q = 0; q < 4; ++q) {
                float4 lo = make_float4(0.f, 0.f, 0.f, 0.f);
                float4 hi = make_float4(0.f, 0.f, 0.f, 0.f);
                if (gr < N) {
                    lo = *(const float4*)&X[(size_t)gr * 128 + co + q * 8];
                    hi = *(const float4*)&X[(size_t)gr * 128 + co + q * 8 + 4];
                }
                __align__(16) __half2 tmp[4];
                tmp[0] = __floats2half2_rn(lo.x, lo.y);
                tmp[1] = __floats2half2_rn(lo.z, lo.w);
                tmp[2] = __floats2half2_rn(hi.x, hi.y);
                tmp[3] = __floats2half2_rn(hi.z, hi.w);
                *(float4*)&Xs[xr][co + q * 8] = *(const float4*)tmp;
            }
        } else {
#pragma unroll
            for (int q = 0; q < 4; ++q) {
                float4 vz = make_float4(0.f, 0.f, 0.f, 0.f);
                if (gr < N)
                    vz = *(const float4*)&X[(size_t)gr * 128 + co + q * 8];
                *(float4*)&Xs[xr][co + q * 8] = vz;
            }
        }
    }
    __syncthreads();

    const int wid = tid >> 6;
    const int lane = tid & 63;
    const int lr = lane & 15, ks = lane >> 4;
    floatx4 acc[8];
#pragma unroll
    for (int t = 0; t < 8; ++t) acc[t] = (floatx4){0.f, 0.f, 0.f, 0.f};

#pragma unroll
    for (int kk = 0; kk < 4; ++kk) {
        half8 a = *(const half8*)&Xs[wid * 16 + lr][kk * 32 + ks * 8];
#pragma unroll
        for (int t = 0; t < 8; ++t) {
            half8 b = *(const half8*)&Ws[t * 16 + lr][kk * 32 + ks * 8];
            acc[t] = __builtin_amdgcn_mfma_f32_16x16x32_f16(a, b, acc[t], 0, 0, 0);
        }
    }
#pragma unroll
    for (int r = 0; r < 4; ++r) {
        int grow = row0 + wid * 16 + ks * 4 + r;
        if (grow < N) {
#pragma unroll
            for (int t = 0; t < 8; ++t)
                C[(size_t)grow * 128 + t * 16 + lr] = __float2half_rn(acc[t][r]);
        }
    }
}

// ---- fused aggregate (r9-proven structure; fp16 hs, templated output) -----
template <typename OutT, bool RELU>
__global__ __launch_bounds__(256) void gat_aggregate_fused(
    const __half* __restrict__ hs, const float* __restrict__ al_s,
    const float* __restrict__ al_d, const int* __restrict__ row_ptr,
    const int* __restrict__ col, const float* __restrict__ bias,
    OutT* __restrict__ out, int N) {
    int node = (int)((blockIdx.x * 256u + threadIdx.x) >> 6);
    int lane = threadIdx.x & 63;
    if (node >= N) return;
    const int begin = row_ptr[node], end = row_ptr[node + 1];
    const float ald = al_d[node];
    const int d0 = lane * 2;

    float acc0 = 0.f, acc1 = 0.f, den = 0.f;
    for (int base = begin; base < end; base += 64) {
        const int cnt = min(64, end - base);
        int myidx = 0;
        float w = 0.f;
        if (lane < cnt) {
            myidx = col[base + lane];
            float l = al_s[myidx] + ald;
            l = (l >= 0.f) ? l : 0.2f * l;
            w = __expf(l);
        }
        float ws = w;
#pragma unroll
        for (int o = 32; o >= 1; o >>= 1) ws += __shfl_xor(ws, o);
        den += ws;

        for (int e = 0; e < cnt; e += 8) {
            __half2 v[8];
            float we[8];
#pragma unroll
            for (int j = 0; j < 8; ++j) {
                int s = __shfl(myidx, e + j);
                we[j] = __shfl(w, e + j);
                v[j] = *(const __half2*)&hs[((size_t)(unsigned)s << 7) + d0];
            }
#pragma unroll
            for (int j = 0; j < 8; ++j) {
                float2 f = __half22float2(v[j]);
                acc0 = fmaf(we[j], f.x, acc0);
                acc1 = fmaf(we[j], f.y, acc1);
            }
        }
    }
    const float rden = (den > 0.f) ? 1.f / den : 0.f;
    float o0 = acc0 * rden + bias[d0];
    float o1 = acc1 * rden + bias[d0 + 1];
    if (RELU) { o0 = fmaxf(o0, 0.f); o1 = fmaxf(o1, 0.f); }
    if constexpr (std::is_same<OutT, __half>::value) {
        *(__half2*)&out[(size_t)node * 128 + d0] = __floats2half2_rn(o0, o1);
    } else {
        *(float2*)&out[(size_t)node * 128 + d0] = make_float2(o0, o1);
    }
}

// ---------------------------------------------------------------------------
extern "C" void kernel_launch(void* const* d_in, const int* in_sizes, int n_in,
                              void* d_out, int out_size, void* d_ws,
                              size_t ws_size, hipStream_t stream) {
    const float* x    = (const float*)d_in[0];
    const int*  eidx  = (const int*)d_in[1];
    const float* W1s  = (const float*)d_in[2];
    const float* W1d  = (const float*)d_in[3];
    const float* a1s  = (const float*)d_in[4];
    const float* a1d  = (const float*)d_in[5];
    const float* b1   = (const float*)d_in[6];
    const float* W2s  = (const float*)d_in[7];
    const float* W2d  = (const float*)d_in[8];
    const float* a2s  = (const float*)d_in[9];
    const float* a2d  = (const float*)d_in[10];
    const float* b2   = (const float*)d_in[11];

    const int N = in_sizes[0] / 128;
    const int E = in_sizes[1] / 2;
    const int* src = eidx;
    const int* dst = eidx + E;

    const int NB   = (N + 255) >> BKT_SHIFT;
    const int NBLK = (E + EPB - 1) / EPB;

    char* p = (char*)d_ws;
    auto alloc = [&](size_t bytes) {
        char* r = p;
        p += (bytes + 255) & ~(size_t)255;
        return r;
    };
    __half* hsA   = (__half*)alloc((size_t)N * 128 * 2);
    __half* h1    = (__half*)alloc((size_t)N * 128 * 2);
    int*   row_ptr= (int*)alloc((size_t)(N + 1) * 4);
    int*   col    = (int*)alloc((size_t)E * 4);
    int*   bpack  = (int*)alloc((size_t)E * 4);
    int*   counts = (int*)alloc((size_t)NBLK * NB * 4);
    int*   totals = (int*)alloc(MAX_NB * 4);
    int*   bbase  = (int*)alloc(MAX_NB * 4);
    float* al_s   = (float*)alloc((size_t)N * 4);
    float* al_d   = (float*)alloc((size_t)N * 4);
    float* wv     = (float*)alloc(4 * 128 * 4);
    __half* wt1   = (__half*)alloc(128 * 128 * 2);
    __half* wt2   = (__half*)alloc(128 * 128 * 2);

    convert_w_kernel<<<32, 256, 0, stream>>>(W1s, W2s, wt1, wt2);
    make_wv4_kernel<<<4, 128, 0, stream>>>(W1s, a1s, W1d, a1d, W2s, a2s, W2d,
                                           a2d, wv);

    bucket_count_kernel<<<NBLK, 256, 0, stream>>>(dst, counts, E, NB);
    bucket_prefix_kernel<<<NB, 256, 0, stream>>>(counts, totals, NBLK, NB);
    bucket_base_kernel<<<1, MAX_NB, 0, stream>>>(totals, bbase, NB);
    bucket_place_kernel<<<NBLK, 256, 0, stream>>>(src, dst, counts, bbase,
                                                  bpack, E, NB);
    bucket_csr_kernel<<<NB, 256, 0, stream>>>(bpack, bbase, row_ptr, col, N, E,
                                              NB);

    const int gemm_grid = (N + 63) / 64;
    const int wave_grid = (N + 3) / 4;

    // ---- layer 1 ----
    gemm_mfma_kernel<float><<<gemm_grid, 256, 0, stream>>>(x, wt1, hsA, N);
    compute_al_kernel<float><<<wave_grid, 256, 0, stream>>>(
        x, wv + 0, wv + 128, al_s, al_d, N);
    gat_aggregate_fused<__half, true><<<wave_grid, 256, 0, stream>>>(
        hsA, al_s, al_d, row_ptr, col, b1, h1, N);

    // ---- layer 2 ----
    gemm_mfma_kernel<__half><<<gemm_grid, 256, 0, stream>>>(h1, wt2, hsA, N);
    compute_al_kernel<__half><<<wave_grid, 256, 0, stream>>>(
        h1, wv + 256, wv + 384, al_s, al_d, N);
    gat_aggregate_fused<float, false><<<wave_grid, 256, 0, stream>>>(
        hsA, al_s, al_d, row_ptr, col, b2, (float*)d_out, N);
}